// Round 5
// baseline (344.743 us; speedup 1.0000x reference)
//
#include <hip/hip_runtime.h>
#include <math.h>

// Rs_GCN, round 5: round 4 with the weh/wel workspace sizing bug fixed
// (each needs B*C*C ushorts = 524,288 float slots; round 4 allocated half,
//  so weh[b>=2] clobbered wel[b<2] -> absmax 7.07).
//   G[b] = Vh (Vh+Vl)^T            (MFMA, atomic accumulate, split-K=8)
//   S'   = Wg G Wph^T + u1 bph^T + bg u2^T + N bg bph^T
//   Weff = (1/N) Ww S' Wth (-> bf16 hi/lo) ; beff = Ww S' bth (atomic)
//   Wy   = (Weh+Wel) Vth + beff/N + bw  (MFMA, BN stats fused) -> BN+residual

#define B_  4
#define C_  512
#define CI_ 256
#define N_  4096

typedef __attribute__((ext_vector_type(8))) short bf16x8;
typedef __attribute__((ext_vector_type(4))) float f32x4;

// ---- ws float offsets -------------------------------------------------------
#define G_OFF     0L          // 1,048,576
#define P1_OFF    1048576L    //   524,288
#define SP_OFF    1572864L    //   262,144
#define P2_OFF    1835008L    //   524,288
#define MISC_OFF  2359296L    //     8,192
#define R_OFF     (MISC_OFF + 0)      // 2048
#define SUM_OFF   (MISC_OFF + 2048)   //  512
#define SSQ_OFF   (MISC_OFF + 2560)   //  512
#define BE_OFF    (MISC_OFF + 3072)   // 2048
#define U1_OFF    (MISC_OFF + 5120)   // 1024
#define U2_OFF    (MISC_OFF + 6144)   // 1024
#define VH_OFF    2367488L    // 4,194,304 float slots (8,388,608 ushort)
#define VL_OFF    6561792L
#define VTH_OFF   10756096L
#define WEH_OFF   14950400L   //   524,288 float slots (1,048,576 ushort)
#define WEL_OFF   15474688L   //   524,288 float slots
// total 15,998,976 floats ~= 64 MB

// ---- helpers ----------------------------------------------------------------
__device__ __forceinline__ unsigned short f2bf(float f) {
    union { float f; unsigned int u; } a; a.f = f;
    unsigned int u = a.u;
    u += 0x7fffu + ((u >> 16) & 1u);      // round-to-nearest-even
    return (unsigned short)(u >> 16);
}
__device__ __forceinline__ float bf2f(unsigned short s) {
    union { unsigned int u; float f; } a; a.u = ((unsigned int)s) << 16; return a.f;
}
__device__ __forceinline__ void gload_lds16(const char* g, char* l) {
    __builtin_amdgcn_global_load_lds(
        (const __attribute__((address_space(1))) unsigned int*)g,
        (__attribute__((address_space(3))) unsigned int*)l, 16, 0, 0);
}

// ---- fused cast: v -> vh,vl ([B][C][N]), vth ([B][N][C]), rowsums r ---------
__global__ __launch_bounds__(256) void cast_fused(
    const float* __restrict__ v, unsigned short* __restrict__ vh,
    unsigned short* __restrict__ vl, unsigned short* __restrict__ vth,
    float* __restrict__ r)
{
    __shared__ float tile[64][65];
    const int b = blockIdx.z;
    const int n0 = blockIdx.x * 64, c0 = blockIdx.y * 64;
    const int t = threadIdx.x, rq = t >> 4, cq = t & 15;
#pragma unroll
    for (int p = 0; p < 4; ++p) {
        int row = p * 16 + rq;
        long e = ((long)(b * C_ + c0 + row)) * N_ + n0 + cq * 4;
        float4 f = *(const float4*)&v[e];
        ushort4 h, l;
        h.x = f2bf(f.x); l.x = f2bf(f.x - bf2f(h.x));
        h.y = f2bf(f.y); l.y = f2bf(f.y - bf2f(h.y));
        h.z = f2bf(f.z); l.z = f2bf(f.z - bf2f(h.z));
        h.w = f2bf(f.w); l.w = f2bf(f.w - bf2f(h.w));
        *(ushort4*)&vh[e] = h;
        *(ushort4*)&vl[e] = l;
        tile[row][cq * 4 + 0] = f.x; tile[row][cq * 4 + 1] = f.y;
        tile[row][cq * 4 + 2] = f.z; tile[row][cq * 4 + 3] = f.w;
        float s = f.x + f.y + f.z + f.w;
        s += __shfl_xor(s, 1); s += __shfl_xor(s, 2);
        s += __shfl_xor(s, 4); s += __shfl_xor(s, 8);
        if (cq == 0) atomicAdd(&r[b * C_ + c0 + row], s);
    }
    __syncthreads();
#pragma unroll
    for (int p = 0; p < 4; ++p) {
        int nl = p * 16 + rq;
        float f0 = tile[cq * 4 + 0][nl], f1 = tile[cq * 4 + 1][nl];
        float f2 = tile[cq * 4 + 2][nl], f3 = tile[cq * 4 + 3][nl];
        ushort4 h;
        h.x = f2bf(f0); h.y = f2bf(f1); h.z = f2bf(f2); h.w = f2bf(f3);
        long e = ((long)(b * N_ + n0 + nl)) * C_ + c0 + cq * 4;
        *(ushort4*)&vth[e] = h;
    }
}

// ---- gram: G[b] += Ah (Bh+Bl)^T tile, 128x64, BK=64, atomic accumulate ------
// grid (8, 4, 32): x=n-tile(64), y=m-tile(128), z=b*8+ch (split-K over N)
__global__ __launch_bounds__(256, 4) void gram_mfma(
    const unsigned short* __restrict__ vh, const unsigned short* __restrict__ vl,
    float* __restrict__ G)
{
    __shared__ char smem[32768];    // Ah 16K | Bh 8K | Bl 8K
    const int t = threadIdx.x, lane = t & 63, w = t >> 6;
    const int z = blockIdx.z, b = z >> 3, ch = z & 7;
    const long m0 = blockIdx.y * 128, n0 = blockIdx.x * 64;
    const long k0b = (long)ch * 1024;                  // 512 elems * 2B
    const long stride = (long)N_ * 2;

    const char* g; char* lbase;
    if (w == 0)      { g = (const char*)(vh + ((long)b * C_ + m0     ) * N_) + k0b; lbase = smem; }
    else if (w == 1) { g = (const char*)(vh + ((long)b * C_ + m0 + 64) * N_) + k0b; lbase = smem + 8192; }
    else if (w == 2) { g = (const char*)(vh + ((long)b * C_ + n0     ) * N_) + k0b; lbase = smem + 16384; }
    else             { g = (const char*)(vl + ((long)b * C_ + n0     ) * N_) + k0b; lbase = smem + 24576; }
    const char* gs = g + (long)(lane >> 3) * stride + (((lane & 7) ^ (lane >> 3)) << 4);

    const int wr = w >> 1, wc = w & 1;
    const int l15 = lane & 15, hi4 = lane >> 4;
    const int swz = (l15 & 7) << 4;
    const int arow = (wr * 64 + l15) * 128;
    const int brow = (wc * 32 + l15) * 128;
    const char* Ah = smem;
    const char* Bh = smem + 16384;
    const char* Bl = smem + 24576;

    f32x4 acc[4][2];
#pragma unroll
    for (int mi = 0; mi < 4; ++mi)
#pragma unroll
        for (int nj = 0; nj < 2; ++nj) acc[mi][nj] = (f32x4){0.f, 0.f, 0.f, 0.f};

    for (int s = 0; s < 8; ++s) {
#pragma unroll
        for (int i = 0; i < 8; ++i)
            gload_lds16(gs + (long)i * 8 * stride + s * 128, lbase + i * 1024);
        __syncthreads();   // drains vmcnt -> LDS writes complete
#pragma unroll
        for (int kk = 0; kk < 2; ++kk) {
            const int off = (kk * 64 + hi4 * 16) ^ swz;
            bf16x8 ah[4], bh[2], bl[2];
#pragma unroll
            for (int mi = 0; mi < 4; ++mi)
                ah[mi] = *(const bf16x8*)(Ah + arow + mi * 2048 + off);
#pragma unroll
            for (int nj = 0; nj < 2; ++nj) {
                bh[nj] = *(const bf16x8*)(Bh + brow + nj * 2048 + off);
                bl[nj] = *(const bf16x8*)(Bl + brow + nj * 2048 + off);
            }
#pragma unroll
            for (int mi = 0; mi < 4; ++mi)
#pragma unroll
                for (int nj = 0; nj < 2; ++nj)
                    acc[mi][nj] = __builtin_amdgcn_mfma_f32_16x16x32_bf16(ah[mi], bh[nj], acc[mi][nj], 0, 0, 0);
#pragma unroll
            for (int mi = 0; mi < 4; ++mi)
#pragma unroll
                for (int nj = 0; nj < 2; ++nj)
                    acc[mi][nj] = __builtin_amdgcn_mfma_f32_16x16x32_bf16(ah[mi], bl[nj], acc[mi][nj], 0, 0, 0);
        }
        __syncthreads();
    }
#pragma unroll
    for (int mi = 0; mi < 4; ++mi)
#pragma unroll
        for (int nj = 0; nj < 2; ++nj)
#pragma unroll
            for (int rr = 0; rr < 4; ++rr) {
                long row = m0 + wr * 64 + mi * 16 + hi4 * 4 + rr;
                long col = n0 + wc * 32 + nj * 16 + l15;
                atomicAdd(&G[((long)b * C_ + row) * C_ + col], acc[mi][nj][rr]);
            }
}

// ---- wy: out = (Weh+Wel) Vth + beff/N + bw ; fused BN stats. 128x64, BK=64 --
// grid (64, 4, 4): x=n-tile(64), y=o-tile(128), z=b
__global__ __launch_bounds__(256, 4) void wy_mfma(
    const unsigned short* __restrict__ weh, const unsigned short* __restrict__ wel,
    const unsigned short* __restrict__ vth,
    const float* __restrict__ be, const float* __restrict__ bw,
    float* __restrict__ out, float* __restrict__ sums, float* __restrict__ ssqs)
{
    __shared__ char smem[40960];    // Weh 16K | Wel 16K | Vh 8K
    const int t = threadIdx.x, lane = t & 63, w = t >> 6;
    const int b = blockIdx.z;
    const long m0 = blockIdx.y * 128;   // o
    const long n0 = blockIdx.x * 64;    // n
    const long S = (long)C_ * 2;        // 1024 B row stride (all three matrices)

    const char* wehb = (const char*)(weh + ((long)b * C_ + m0) * C_);
    const char* welb = (const char*)(wel + ((long)b * C_ + m0) * C_);
    const char* vhb  = (const char*)(vth + ((long)b * N_ + n0) * C_);

    // balanced staging: 40 x 1KB groups over 4 waves (10 each), 2 segments max
    const char *g0, *g1; char *l0, *l1; int c0n;
    if (w == 0)      { g0 = wehb;           l0 = smem;                 c0n = 10; g1 = wehb; l1 = smem; }
    else if (w == 1) { g0 = wehb + 80 * S;  l0 = smem + 10240;         c0n = 6;  g1 = welb;          l1 = smem + 16384; }
    else if (w == 2) { g0 = welb + 32 * S;  l0 = smem + 16384 + 4096;  c0n = 10; g1 = welb; l1 = smem + 16384; }
    else             { g0 = welb + 112 * S; l0 = smem + 16384 + 14336; c0n = 2;  g1 = vhb;           l1 = smem + 32768; }
    const long plane = (long)(lane >> 3) * S + (((lane & 7) ^ (lane >> 3)) << 4);

    const int wr = w >> 1, wc = w & 1;
    const int l15 = lane & 15, hi4 = lane >> 4;
    const int swz = (l15 & 7) << 4;
    const int arow = (wr * 64 + l15) * 128;
    const int brow = (wc * 32 + l15) * 128;
    const char* Ah = smem;
    const char* Al = smem + 16384;
    const char* Bv = smem + 32768;

    f32x4 acc[4][2];
#pragma unroll
    for (int mi = 0; mi < 4; ++mi)
#pragma unroll
        for (int nj = 0; nj < 2; ++nj) acc[mi][nj] = (f32x4){0.f, 0.f, 0.f, 0.f};

    for (int s = 0; s < 8; ++s) {
#pragma unroll
        for (int i = 0; i < 10; ++i) {
            const char* src; char* dst;
            if (i < c0n) { src = g0 + (long)i * 8 * S;         dst = l0 + i * 1024; }
            else         { src = g1 + (long)(i - c0n) * 8 * S; dst = l1 + (i - c0n) * 1024; }
            gload_lds16(src + plane + s * 128, dst);
        }
        __syncthreads();
#pragma unroll
        for (int kk = 0; kk < 2; ++kk) {
            const int off = (kk * 64 + hi4 * 16) ^ swz;
            bf16x8 ah[4], al[4], bv[2];
#pragma unroll
            for (int mi = 0; mi < 4; ++mi) {
                ah[mi] = *(const bf16x8*)(Ah + arow + mi * 2048 + off);
                al[mi] = *(const bf16x8*)(Al + arow + mi * 2048 + off);
            }
#pragma unroll
            for (int nj = 0; nj < 2; ++nj)
                bv[nj] = *(const bf16x8*)(Bv + brow + nj * 2048 + off);
#pragma unroll
            for (int mi = 0; mi < 4; ++mi)
#pragma unroll
                for (int nj = 0; nj < 2; ++nj)
                    acc[mi][nj] = __builtin_amdgcn_mfma_f32_16x16x32_bf16(ah[mi], bv[nj], acc[mi][nj], 0, 0, 0);
#pragma unroll
            for (int mi = 0; mi < 4; ++mi)
#pragma unroll
                for (int nj = 0; nj < 2; ++nj)
                    acc[mi][nj] = __builtin_amdgcn_mfma_f32_16x16x32_bf16(al[mi], bv[nj], acc[mi][nj], 0, 0, 0);
        }
        __syncthreads();
    }

    float sm[4][4], sq[4][4];
#pragma unroll
    for (int mi = 0; mi < 4; ++mi)
#pragma unroll
        for (int rr = 0; rr < 4; ++rr) { sm[mi][rr] = 0.f; sq[mi][rr] = 0.f; }

#pragma unroll
    for (int mi = 0; mi < 4; ++mi) {
#pragma unroll
        for (int rr = 0; rr < 4; ++rr) {
            long o = m0 + wr * 64 + mi * 16 + hi4 * 4 + rr;
            float bv = be[b * C_ + o] * (1.0f / (float)N_) + bw[o];
#pragma unroll
            for (int nj = 0; nj < 2; ++nj) {
                long n = n0 + wc * 32 + nj * 16 + l15;
                float val = acc[mi][nj][rr] + bv;
                out[((long)b * C_ + o) * N_ + n] = val;
                sm[mi][rr] += val;
                sq[mi][rr] += val * val;
            }
        }
    }
#pragma unroll
    for (int mi = 0; mi < 4; ++mi)
#pragma unroll
        for (int rr = 0; rr < 4; ++rr) {
            float s1 = sm[mi][rr], s2 = sq[mi][rr];
            s1 += __shfl_xor(s1, 1); s2 += __shfl_xor(s2, 1);
            s1 += __shfl_xor(s1, 2); s2 += __shfl_xor(s2, 2);
            s1 += __shfl_xor(s1, 4); s2 += __shfl_xor(s2, 4);
            s1 += __shfl_xor(s1, 8); s2 += __shfl_xor(s2, 8);
            if (l15 == 0) {
                long o = m0 + wr * 64 + mi * 16 + hi4 * 4 + rr;
                atomicAdd(&sums[o], s1);
                atomicAdd(&ssqs[o], s2);
            }
        }
}

// ---- NN gemm 64x64: C[m][n] = scale * sum_k A[m][k] B[k][n] + epilogues -----
// mode 0: write C. mode 1: write C + beff atomic (bth,be). mode 2: hi/lo cast.
__global__ __launch_bounds__(256) void gemm_nn(
    const float* __restrict__ A, long sA, int lda,
    const float* __restrict__ Bm, long sB, int ldb,
    float* __restrict__ Cm, long sC, int ldc,
    int K, float scale, int mode,
    const float* __restrict__ bth, float* __restrict__ be,
    unsigned short* __restrict__ weh, unsigned short* __restrict__ wel)
{
    int b = blockIdx.z;
    const float* Ab = A + (long)b * sA;
    const float* Bb = Bm + (long)b * sB;
    int i0 = blockIdx.y * 64, j0 = blockIdx.x * 64;

    __shared__ __align__(16) float As[16][64];
    __shared__ __align__(16) float Bs[16][64];

    int t = threadIdx.x, tx = t & 15, ty = t >> 4;
    int am = t >> 2, akq = (t & 3) << 2;
    int bk = t >> 4, bn4 = (t & 15) << 2;

    float acc[4][4];
#pragma unroll
    for (int r = 0; r < 4; ++r)
#pragma unroll
        for (int c = 0; c < 4; ++c) acc[r][c] = 0.f;

    for (int k0 = 0; k0 < K; k0 += 16) {
        float4 va = *(const float4*)&Ab[(long)(i0 + am) * lda + k0 + akq];
        As[akq + 0][am] = va.x; As[akq + 1][am] = va.y;
        As[akq + 2][am] = va.z; As[akq + 3][am] = va.w;
        *(float4*)&Bs[bk][bn4] = *(const float4*)&Bb[(long)(k0 + bk) * ldb + j0 + bn4];
        __syncthreads();
#pragma unroll
        for (int k = 0; k < 16; ++k) {
            float4 a4 = *(float4*)&As[k][ty * 4];
            float4 b4 = *(float4*)&Bs[k][tx * 4];
            float a[4]  = {a4.x, a4.y, a4.z, a4.w};
            float bb[4] = {b4.x, b4.y, b4.z, b4.w};
#pragma unroll
            for (int r = 0; r < 4; ++r)
#pragma unroll
                for (int c = 0; c < 4; ++c)
                    acc[r][c] += a[r] * bb[c];
        }
        __syncthreads();
    }

    if (mode == 2) {   // Weff -> bf16 hi/lo, [b][o=i][p=j]
#pragma unroll
        for (int r = 0; r < 4; ++r) {
            int o = i0 + ty * 4 + r, p = j0 + tx * 4;
            ushort4 h, l;
            float f0 = acc[r][0] * scale, f1 = acc[r][1] * scale;
            float f2 = acc[r][2] * scale, f3 = acc[r][3] * scale;
            h.x = f2bf(f0); l.x = f2bf(f0 - bf2f(h.x));
            h.y = f2bf(f1); l.y = f2bf(f1 - bf2f(h.y));
            h.z = f2bf(f2); l.z = f2bf(f2 - bf2f(h.z));
            h.w = f2bf(f3); l.w = f2bf(f3 - bf2f(h.w));
            long e = (((long)b * C_ + o) * C_ + p) >> 2;
            ((ushort4*)weh)[e] = h;
            ((ushort4*)wel)[e] = l;
        }
        return;
    }
    float* Cb = Cm + (long)b * sC;
#pragma unroll
    for (int r = 0; r < 4; ++r) {
        float4 o0 = make_float4(acc[r][0] * scale, acc[r][1] * scale,
                                acc[r][2] * scale, acc[r][3] * scale);
        *(float4*)&Cb[(long)(i0 + ty * 4 + r) * ldc + j0 + tx * 4] = o0;
    }
    if (mode == 1) {   // beff partial: be[o] += sum_i C[o][i]*bth[i]
#pragma unroll
        for (int r = 0; r < 4; ++r) {
            float pr = acc[r][0] * bth[j0 + tx * 4 + 0]
                     + acc[r][1] * bth[j0 + tx * 4 + 1]
                     + acc[r][2] * bth[j0 + tx * 4 + 2]
                     + acc[r][3] * bth[j0 + tx * 4 + 3];
            pr += __shfl_xor(pr, 1); pr += __shfl_xor(pr, 2);
            pr += __shfl_xor(pr, 4); pr += __shfl_xor(pr, 8);
            if (tx == 0) atomicAdd(&be[b * C_ + i0 + ty * 4 + r], pr);
        }
    }
}

// ---- SP (NT) = P1 Wph^T + rank-1 epilogue -----------------------------------
__global__ __launch_bounds__(256) void gemm_nt_sp(
    const float* __restrict__ P1, const float* __restrict__ Wph,
    float* __restrict__ SP, const float* __restrict__ u1,
    const float* __restrict__ u2, const float* __restrict__ bg,
    const float* __restrict__ bph)
{
    int b = blockIdx.z;
    const float* Ab = P1 + (long)b * (CI_ * C_);
    int i0 = blockIdx.y * 64, j0 = blockIdx.x * 64;

    __shared__ __align__(16) float As[16][64];
    __shared__ __align__(16) float Bs[16][64];

    int t = threadIdx.x, tx = t & 15, ty = t >> 4;
    int lr = t >> 2, lk = (t & 3) << 2;

    float acc[4][4];
#pragma unroll
    for (int r = 0; r < 4; ++r)
#pragma unroll
        for (int c = 0; c < 4; ++c) acc[r][c] = 0.f;

    for (int kt = 0; kt < C_; kt += 16) {
        float4 va = *(const float4*)&Ab[(long)(i0 + lr) * C_ + kt + lk];
        float4 vb = *(const float4*)&Wph[(long)(j0 + lr) * C_ + kt + lk];
        As[lk + 0][lr] = va.x; As[lk + 1][lr] = va.y; As[lk + 2][lr] = va.z; As[lk + 3][lr] = va.w;
        Bs[lk + 0][lr] = vb.x; Bs[lk + 1][lr] = vb.y; Bs[lk + 2][lr] = vb.z; Bs[lk + 3][lr] = vb.w;
        __syncthreads();
#pragma unroll
        for (int k = 0; k < 16; ++k) {
            float4 a4 = *(float4*)&As[k][ty * 4];
            float4 b4 = *(float4*)&Bs[k][tx * 4];
            float a[4]  = {a4.x, a4.y, a4.z, a4.w};
            float bb[4] = {b4.x, b4.y, b4.z, b4.w};
#pragma unroll
            for (int r = 0; r < 4; ++r)
#pragma unroll
                for (int c = 0; c < 4; ++c)
                    acc[r][c] += a[r] * bb[c];
        }
        __syncthreads();
    }
    float* Cb = SP + (long)b * (CI_ * CI_);
#pragma unroll
    for (int r = 0; r < 4; ++r) {
        int cr = i0 + ty * 4 + r;
        float u1v = u1[b * CI_ + cr], bgv = bg[cr];
        float4 o0;
        float* po = (float*)&o0;
#pragma unroll
        for (int c = 0; c < 4; ++c) {
            int ic = j0 + tx * 4 + c;
            po[c] = acc[r][c] + u1v * bph[ic] + bgv * (u2[b * CI_ + ic] + (float)N_ * bph[ic]);
        }
        *(float4*)&Cb[(long)cr * CI_ + j0 + tx * 4] = o0;
    }
}

// ---- rank1_prep: u1 = Wg r, u2 = Wph r --------------------------------------
__global__ __launch_bounds__(256) void rank1_prep(
    const float* __restrict__ Wg, const float* __restrict__ Wph,
    const float* __restrict__ r, float* __restrict__ u1, float* __restrict__ u2)
{
    int blk = blockIdx.x;                 // 16 = 4 b x 4 quarters
    int b = blk >> 2, q = blk & 3;
    int t = threadIdx.x;
    int c = q * 64 + (t >> 2);            // Ci index
    int kq = t & 3;                       // k-quarter (128 each)
    const float* rb = r + b * C_;
    float s1 = 0.f, s2 = 0.f;
    for (int k = kq * 128; k < kq * 128 + 128; k += 4) {
        float4 wg = *(const float4*)&Wg[(long)c * C_ + k];
        float4 wp = *(const float4*)&Wph[(long)c * C_ + k];
        float4 rv = *(const float4*)&rb[k];
        s1 += wg.x * rv.x + wg.y * rv.y + wg.z * rv.z + wg.w * rv.w;
        s2 += wp.x * rv.x + wp.y * rv.y + wp.z * rv.z + wp.w * rv.w;
    }
    s1 += __shfl_xor(s1, 1); s2 += __shfl_xor(s2, 1);
    s1 += __shfl_xor(s1, 2); s2 += __shfl_xor(s2, 2);
    if (kq == 0) {
        u1[b * CI_ + c] = s1;
        u2[b * CI_ + c] = s2;
    }
}

// ---- bn_apply with inline finalize: out = out*sc + sh + v -------------------
__global__ __launch_bounds__(256) void bn_apply(
    float* __restrict__ out, const float* __restrict__ v,
    const float* __restrict__ sums, const float* __restrict__ ssqs,
    const float* __restrict__ gamma, const float* __restrict__ beta)
{
    long i = (long)blockIdx.x * 256 + threadIdx.x;     // float4 index
    int o = (int)((i >> 10) & (C_ - 1));
    const float inv = 1.0f / ((float)B_ * (float)N_);
    float mean = sums[o] * inv;
    float var  = ssqs[o] * inv - mean * mean;
    float sc = gamma[o] * rsqrtf(var + 1e-5f);
    float sh = beta[o] - mean * sc;
    float4 wv = ((const float4*)out)[i];
    float4 vv = ((const float4*)v)[i];
    wv.x = wv.x * sc + sh + vv.x;
    wv.y = wv.y * sc + sh + vv.y;
    wv.z = wv.z * sc + sh + vv.z;
    wv.w = wv.w * sc + sh + vv.w;
    ((float4*)out)[i] = wv;
}

// ---- launch -----------------------------------------------------------------
extern "C" void kernel_launch(void* const* d_in, const int* in_sizes, int n_in,
                              void* d_out, int out_size, void* d_ws, size_t ws_size,
                              hipStream_t stream)
{
    const float* v     = (const float*)d_in[0];
    const float* Wg    = (const float*)d_in[1];
    const float* bg    = (const float*)d_in[2];
    const float* Wth   = (const float*)d_in[3];
    const float* bth   = (const float*)d_in[4];
    const float* Wph   = (const float*)d_in[5];
    const float* bph   = (const float*)d_in[6];
    const float* Ww    = (const float*)d_in[7];
    const float* bw    = (const float*)d_in[8];
    const float* gamma = (const float*)d_in[9];
    const float* beta  = (const float*)d_in[10];
    float* out = (float*)d_out;
    float* ws  = (float*)d_ws;

    float* G    = ws + G_OFF;
    float* P1   = ws + P1_OFF;
    float* SP   = ws + SP_OFF;
    float* P2   = ws + P2_OFF;
    float* r    = ws + R_OFF;
    float* sums = ws + SUM_OFF;
    float* ssqs = ws + SSQ_OFF;
    float* be   = ws + BE_OFF;
    float* u1   = ws + U1_OFF;
    float* u2   = ws + U2_OFF;
    unsigned short* vh  = (unsigned short*)(ws + VH_OFF);
    unsigned short* vl  = (unsigned short*)(ws + VL_OFF);
    unsigned short* vth = (unsigned short*)(ws + VTH_OFF);
    unsigned short* weh = (unsigned short*)(ws + WEH_OFF);
    unsigned short* wel = (unsigned short*)(ws + WEL_OFF);

    // zero: G (atomic target) + misc (r, sums, ssqs, be)
    hipMemsetAsync(G, 0, 1048576 * sizeof(float), stream);
    hipMemsetAsync(r, 0, 5120 * sizeof(float), stream);

    // v -> vh, vl, vth, rowsums (one pass)
    cast_fused<<<dim3(64, 8, 4), 256, 0, stream>>>(v, vh, vl, vth, r);

    // G = Vh (Vh+Vl)^T  (atomic accumulate over 8 K-chunks)
    gram_mfma<<<dim3(8, 4, 32), 256, 0, stream>>>(vh, vl, G);

    // u1 = Wg r, u2 = Wph r
    rank1_prep<<<16, 256, 0, stream>>>(Wg, Wph, r, u1, u2);

    // P1 = Wg G   [256x512]
    gemm_nn<<<dim3(8, 4, 4), 256, 0, stream>>>(
        Wg, 0, C_, G, (long)C_ * C_, C_, P1, (long)CI_ * C_, C_,
        C_, 1.0f, 0, nullptr, nullptr, nullptr, nullptr);

    // S' = P1 Wph^T + rank-1   [256x256]
    gemm_nt_sp<<<dim3(4, 4, 4), 256, 0, stream>>>(P1, Wph, SP, u1, u2, bg, bph);

    // P2 = Ww S'  [512x256]  + beff atomics
    gemm_nn<<<dim3(4, 8, 4), 256, 0, stream>>>(
        Ww, 0, CI_, SP, (long)CI_ * CI_, CI_, P2, (long)C_ * CI_, CI_,
        CI_, 1.0f, 1, bth, be, nullptr, nullptr);

    // Weff = (1/N) P2 Wth -> bf16 hi/lo  [512x512]
    gemm_nn<<<dim3(8, 8, 4), 256, 0, stream>>>(
        P2, (long)C_ * CI_, CI_, Wth, 0, C_, nullptr, 0, 0,
        CI_, 1.0f / (float)N_, 2, nullptr, nullptr, weh, wel);

    // Wy + fused BN stats
    wy_mfma<<<dim3(64, 4, 4), 256, 0, stream>>>(weh, wel, vth, be, bw, out, sums, ssqs);

    // BN finalize+apply (+ residual)
    bn_apply<<<8192, 256, 0, stream>>>(out, v, sums, ssqs, gamma, beta);
}

// Round 6
// 309.840 us; speedup vs baseline: 1.1126x; 1.1126x over previous
//
#include <hip/hip_runtime.h>
#include <math.h>

// Rs_GCN, round 6:
//  - wy/gram back to proven 128x128 4-wave BK=64 structure (round-3 core), 2-term hi/lo
//  - gram: symmetric lower-triangle only (10/16 tiles), split-K=16, + mirror kernel
//  - BN stats computed ANALYTICALLY before wy (mean from Weff*r, ssq from diag(Weff G Weff^T)
//    via H = Weff*G MFMA using G's symmetry) -> wy epilogue applies BN+residual, bn_apply pass deleted.
//   G[b] = Vh (Vh+Vl)^T   (lower tiles, atomic, split-K=16) -> mirror
//   S'   = Wg G Wph^T + u1 bph^T + bg u2^T + N bg bph^T
//   Weff = (1/N) Ww S' Wth (-> bf16 hi/lo) ; be = Ww S' bth (atomic)
//   H    = (Weh+Wel) Gh ; QF/MV -> sc,sh
//   out  = ((Weh+Wel) Vth + bfull)*sc + sh + v

#define B_  4
#define C_  512
#define CI_ 256
#define N_  4096

typedef __attribute__((ext_vector_type(8))) short bf16x8;
typedef __attribute__((ext_vector_type(4))) float f32x4;

// ---- ws float offsets (recomputed & audited) --------------------------------
#define G_OFF     0L          // 1,048,576  [B][512][512] fp32
#define GH_OFF    1048576L    //   524,288  (1,048,576 ushort)
#define H_OFF     1572864L    // 1,048,576  [B][512][512] fp32
#define P1_OFF    2621440L    //   524,288
#define SP_OFF    3145728L    //   262,144
#define P2_OFF    3407872L    //   524,288
#define MISC_OFF  3932160L    //    12,288 reserved
#define R_OFF     (MISC_OFF + 0)      // 2048
#define BE_OFF    (MISC_OFF + 2048)   // 2048
#define U1_OFF    (MISC_OFF + 4096)   // 1024
#define U2_OFF    (MISC_OFF + 5120)   // 1024
#define QF_OFF    (MISC_OFF + 6144)   // 2048
#define MV_OFF    (MISC_OFF + 8192)   // 2048
#define SC_OFF    (MISC_OFF + 10240)  //  512
#define SH_OFF    (MISC_OFF + 10752)  //  512
#define VH_OFF    3944448L    // 4,194,304 (8,388,608 ushort)
#define VL_OFF    8138752L
#define VTH_OFF   12333056L
#define WEH_OFF   16527360L   //   524,288 (1,048,576 ushort)
#define WEL_OFF   17051648L   //   524,288
// total 17,575,936 floats ~= 70.3 MB

// ---- helpers ----------------------------------------------------------------
__device__ __forceinline__ unsigned short f2bf(float f) {
    union { float f; unsigned int u; } a; a.f = f;
    unsigned int u = a.u;
    u += 0x7fffu + ((u >> 16) & 1u);
    return (unsigned short)(u >> 16);
}
__device__ __forceinline__ float bf2f(unsigned short s) {
    union { unsigned int u; float f; } a; a.u = ((unsigned int)s) << 16; return a.f;
}
__device__ __forceinline__ void gload_lds16(const char* g, char* l) {
    __builtin_amdgcn_global_load_lds(
        (const __attribute__((address_space(1))) unsigned int*)g,
        (__attribute__((address_space(3))) unsigned int*)l, 16, 0, 0);
}

// ---- fused cast: v -> vh,vl ([B][C][N]), vth ([B][N][C]), rowsums r ---------
__global__ __launch_bounds__(256) void cast_fused(
    const float* __restrict__ v, unsigned short* __restrict__ vh,
    unsigned short* __restrict__ vl, unsigned short* __restrict__ vth,
    float* __restrict__ r)
{
    __shared__ float tile[64][65];
    const int b = blockIdx.z;
    const int n0 = blockIdx.x * 64, c0 = blockIdx.y * 64;
    const int t = threadIdx.x, rq = t >> 4, cq = t & 15;
#pragma unroll
    for (int p = 0; p < 4; ++p) {
        int row = p * 16 + rq;
        long e = ((long)(b * C_ + c0 + row)) * N_ + n0 + cq * 4;
        float4 f = *(const float4*)&v[e];
        ushort4 h, l;
        h.x = f2bf(f.x); l.x = f2bf(f.x - bf2f(h.x));
        h.y = f2bf(f.y); l.y = f2bf(f.y - bf2f(h.y));
        h.z = f2bf(f.z); l.z = f2bf(f.z - bf2f(h.z));
        h.w = f2bf(f.w); l.w = f2bf(f.w - bf2f(h.w));
        *(ushort4*)&vh[e] = h;
        *(ushort4*)&vl[e] = l;
        tile[row][cq * 4 + 0] = f.x; tile[row][cq * 4 + 1] = f.y;
        tile[row][cq * 4 + 2] = f.z; tile[row][cq * 4 + 3] = f.w;
        float s = f.x + f.y + f.z + f.w;
        s += __shfl_xor(s, 1); s += __shfl_xor(s, 2);
        s += __shfl_xor(s, 4); s += __shfl_xor(s, 8);
        if (cq == 0) atomicAdd(&r[b * C_ + c0 + row], s);
    }
    __syncthreads();
#pragma unroll
    for (int p = 0; p < 4; ++p) {
        int nl = p * 16 + rq;
        float f0 = tile[cq * 4 + 0][nl], f1 = tile[cq * 4 + 1][nl];
        float f2 = tile[cq * 4 + 2][nl], f3 = tile[cq * 4 + 3][nl];
        ushort4 h;
        h.x = f2bf(f0); h.y = f2bf(f1); h.z = f2bf(f2); h.w = f2bf(f3);
        long e = ((long)(b * N_ + n0 + nl)) * C_ + c0 + cq * 4;
        *(ushort4*)&vth[e] = h;
    }
}

// ---- gram: lower-triangle 128x128 tiles, 2-term, split-K=16, atomics --------
// grid (10, 1, 64): x = pair idx, z = b*16+ch (chunk of 256 elems). 4 s-steps.
__global__ __launch_bounds__(256, 2) void gram_mfma(
    const unsigned short* __restrict__ vh, const unsigned short* __restrict__ vl,
    float* __restrict__ G)
{
    __shared__ char smem[49152];    // Ah 16K | Bh 16K | Bl 16K
    const int MT[10] = {0,1,1,2,2,2,3,3,3,3};
    const int NT[10] = {0,0,1,0,1,2,0,1,2,3};
    const int t = threadIdx.x, lane = t & 63, w = t >> 6;
    const int z = blockIdx.z, b = z >> 4, ch = z & 15;
    const long m0 = MT[blockIdx.x] * 128, n0 = NT[blockIdx.x] * 128;
    const long k0b = (long)ch * 512;                   // 256 elems * 2B
    const long stride = (long)N_ * 2;                  // 8192 B

    const char* vhm = (const char*)(vh + ((long)b * C_ + m0) * N_) + k0b;
    const char* vhn = (const char*)(vh + ((long)b * C_ + n0) * N_) + k0b;
    const char* vln = (const char*)(vl + ((long)b * C_ + n0) * N_) + k0b;
    char* AhL = smem; char* BhL = smem + 16384; char* BlL = smem + 32768;

    const char *g0, *g1; char *l0, *l1; int c0n;
    if (w == 0)      { g0 = vhm;                l0 = AhL;             c0n = 12; g1 = g0;  l1 = l0; }
    else if (w == 1) { g0 = vhm + 96 * stride;  l0 = AhL + 12 * 1024; c0n = 4;  g1 = vhn; l1 = BhL; }
    else if (w == 2) { g0 = vhn + 64 * stride;  l0 = BhL + 8 * 1024;  c0n = 8;  g1 = vln; l1 = BlL; }
    else             { g0 = vln + 32 * stride;  l0 = BlL + 4 * 1024;  c0n = 12; g1 = g0;  l1 = l0; }
    const long plane = (long)(lane >> 3) * stride + (((lane & 7) ^ (lane >> 3)) << 4);

    const int wr = w >> 1, wc = w & 1;
    const int l15 = lane & 15, hi4 = lane >> 4;
    const int swz = (l15 & 7) << 4;
    const int arow = (wr * 64 + l15) * 128;
    const int brow = (wc * 64 + l15) * 128;

    f32x4 acc[4][4];
#pragma unroll
    for (int mi = 0; mi < 4; ++mi)
#pragma unroll
        for (int nj = 0; nj < 4; ++nj) acc[mi][nj] = (f32x4){0.f, 0.f, 0.f, 0.f};

    for (int s = 0; s < 4; ++s) {
#pragma unroll
        for (int i = 0; i < 12; ++i) {
            const char* src; char* dst;
            if (i < c0n) { src = g0 + (long)i * 8 * stride;         dst = l0 + i * 1024; }
            else         { src = g1 + (long)(i - c0n) * 8 * stride; dst = l1 + (i - c0n) * 1024; }
            gload_lds16(src + plane + s * 128, dst);
        }
        __syncthreads();
#pragma unroll
        for (int kk = 0; kk < 2; ++kk) {
            const int off = (kk * 64 + hi4 * 16) ^ swz;
            bf16x8 ah[4], bh[4], bl[4];
#pragma unroll
            for (int mi = 0; mi < 4; ++mi)
                ah[mi] = *(const bf16x8*)(AhL + arow + mi * 2048 + off);
#pragma unroll
            for (int nj = 0; nj < 4; ++nj) {
                bh[nj] = *(const bf16x8*)(BhL + brow + nj * 2048 + off);
                bl[nj] = *(const bf16x8*)(BlL + brow + nj * 2048 + off);
            }
#pragma unroll
            for (int mi = 0; mi < 4; ++mi)
#pragma unroll
                for (int nj = 0; nj < 4; ++nj)
                    acc[mi][nj] = __builtin_amdgcn_mfma_f32_16x16x32_bf16(ah[mi], bh[nj], acc[mi][nj], 0, 0, 0);
#pragma unroll
            for (int mi = 0; mi < 4; ++mi)
#pragma unroll
                for (int nj = 0; nj < 4; ++nj)
                    acc[mi][nj] = __builtin_amdgcn_mfma_f32_16x16x32_bf16(ah[mi], bl[nj], acc[mi][nj], 0, 0, 0);
        }
        __syncthreads();
    }
#pragma unroll
    for (int mi = 0; mi < 4; ++mi)
#pragma unroll
        for (int nj = 0; nj < 4; ++nj)
#pragma unroll
            for (int rr = 0; rr < 4; ++rr) {
                long row = m0 + wr * 64 + mi * 16 + hi4 * 4 + rr;
                long col = n0 + wc * 64 + nj * 16 + l15;
                atomicAdd(&G[((long)b * C_ + row) * C_ + col], acc[mi][nj][rr]);
            }
}

// ---- mirror: G upper = G lower^T. grid (8 J, 8 I, 4 b), skip I>J ------------
__global__ __launch_bounds__(256) void mirror_g(float* __restrict__ G)
{
    const int J = blockIdx.x, I = blockIdx.y, b = blockIdx.z;
    if (I > J) return;
    __shared__ float tile[64][65];
    const int t = threadIdx.x, ty = t >> 4, tx = t & 15;
    float* Gb = G + (long)b * C_ * C_;
#pragma unroll
    for (int p = 0; p < 4; ++p) {
        int row = p * 16 + ty;     // src row local (j)
        *(float4*)&tile[row][tx * 4] =
            *(const float4*)&Gb[(long)(J * 64 + row) * C_ + I * 64 + tx * 4];
    }
    __syncthreads();
    if (I < J) {
#pragma unroll
        for (int p = 0; p < 4; ++p) {
            int row = p * 16 + ty;  // dst row local (i)
            float4 o = make_float4(tile[tx * 4 + 0][row], tile[tx * 4 + 1][row],
                                   tile[tx * 4 + 2][row], tile[tx * 4 + 3][row]);
            *(float4*)&Gb[(long)(I * 64 + row) * C_ + J * 64 + tx * 4] = o;
        }
    } else {   // diagonal tile: copy only strictly-upper elements
#pragma unroll
        for (int p = 0; p < 4; ++p) {
            int row = p * 16 + ty;
            int i = I * 64 + row;
#pragma unroll
            for (int c = 0; c < 4; ++c) {
                int j = J * 64 + tx * 4 + c;
                if (i < j) Gb[(long)i * C_ + j] = tile[tx * 4 + c][row];
            }
        }
    }
}

// ---- g_cast: G (fp32) -> Gh (bf16 hi) ---------------------------------------
__global__ __launch_bounds__(256) void g_cast(
    const float* __restrict__ G, unsigned short* __restrict__ Gh)
{
    long idx = (long)blockIdx.x * 256 + threadIdx.x;   // float4 idx, 262,144
    float4 f = ((const float4*)G)[idx];
    ushort4 h;
    h.x = f2bf(f.x); h.y = f2bf(f.y); h.z = f2bf(f.z); h.w = f2bf(f.w);
    ((ushort4*)Gh)[idx] = h;
}

// ---- h_mfma: H[b] = (Weh+Wel) Gh   (G symmetric -> rows as B-operand) -------
// grid (4, 4, 4): x = n-tile(128) of 512, y = o-tile(128), z = b. K=512, 8 s-steps.
__global__ __launch_bounds__(256, 2) void h_mfma(
    const unsigned short* __restrict__ weh, const unsigned short* __restrict__ wel,
    const unsigned short* __restrict__ Gh, float* __restrict__ H)
{
    __shared__ char smem[49152];    // Ah | Al | Bh
    const int t = threadIdx.x, lane = t & 63, w = t >> 6;
    const int b = blockIdx.z;
    const long m0 = blockIdx.y * 128, n0 = blockIdx.x * 128;
    const long S = (long)C_ * 2;    // 1024 B

    const char* wehb = (const char*)(weh + ((long)b * C_ + m0) * C_);
    const char* welb = (const char*)(wel + ((long)b * C_ + m0) * C_);
    const char* ghb  = (const char*)(Gh  + ((long)b * C_ + n0) * C_);
    char* AhL = smem; char* AlL = smem + 16384; char* BhL = smem + 32768;

    const char *g0, *g1; char *l0, *l1; int c0n;
    if (w == 0)      { g0 = wehb;          l0 = AhL;             c0n = 12; g1 = g0;   l1 = l0; }
    else if (w == 1) { g0 = wehb + 96 * S; l0 = AhL + 12 * 1024; c0n = 4;  g1 = welb; l1 = AlL; }
    else if (w == 2) { g0 = welb + 64 * S; l0 = AlL + 8 * 1024;  c0n = 8;  g1 = ghb;  l1 = BhL; }
    else             { g0 = ghb + 32 * S;  l0 = BhL + 4 * 1024;  c0n = 12; g1 = g0;   l1 = l0; }
    const long plane = (long)(lane >> 3) * S + (((lane & 7) ^ (lane >> 3)) << 4);

    const int wr = w >> 1, wc = w & 1;
    const int l15 = lane & 15, hi4 = lane >> 4;
    const int swz = (l15 & 7) << 4;
    const int arow = (wr * 64 + l15) * 128;
    const int brow = (wc * 64 + l15) * 128;

    f32x4 acc[4][4];
#pragma unroll
    for (int mi = 0; mi < 4; ++mi)
#pragma unroll
        for (int nj = 0; nj < 4; ++nj) acc[mi][nj] = (f32x4){0.f, 0.f, 0.f, 0.f};

    for (int s = 0; s < 8; ++s) {
#pragma unroll
        for (int i = 0; i < 12; ++i) {
            const char* src; char* dst;
            if (i < c0n) { src = g0 + (long)i * 8 * S;         dst = l0 + i * 1024; }
            else         { src = g1 + (long)(i - c0n) * 8 * S; dst = l1 + (i - c0n) * 1024; }
            gload_lds16(src + plane + s * 128, dst);
        }
        __syncthreads();
#pragma unroll
        for (int kk = 0; kk < 2; ++kk) {
            const int off = (kk * 64 + hi4 * 16) ^ swz;
            bf16x8 ah[4], al[4], bh[4];
#pragma unroll
            for (int mi = 0; mi < 4; ++mi) {
                ah[mi] = *(const bf16x8*)(AhL + arow + mi * 2048 + off);
                al[mi] = *(const bf16x8*)(AlL + arow + mi * 2048 + off);
            }
#pragma unroll
            for (int nj = 0; nj < 4; ++nj)
                bh[nj] = *(const bf16x8*)(BhL + brow + nj * 2048 + off);
#pragma unroll
            for (int mi = 0; mi < 4; ++mi)
#pragma unroll
                for (int nj = 0; nj < 4; ++nj)
                    acc[mi][nj] = __builtin_amdgcn_mfma_f32_16x16x32_bf16(ah[mi], bh[nj], acc[mi][nj], 0, 0, 0);
#pragma unroll
            for (int mi = 0; mi < 4; ++mi)
#pragma unroll
                for (int nj = 0; nj < 4; ++nj)
                    acc[mi][nj] = __builtin_amdgcn_mfma_f32_16x16x32_bf16(al[mi], bh[nj], acc[mi][nj], 0, 0, 0);
        }
        __syncthreads();
    }
#pragma unroll
    for (int mi = 0; mi < 4; ++mi)
#pragma unroll
        for (int nj = 0; nj < 4; ++nj)
#pragma unroll
            for (int rr = 0; rr < 4; ++rr) {
                long row = m0 + wr * 64 + mi * 16 + hi4 * 4 + rr;
                long col = n0 + wc * 64 + nj * 16 + l15;
                H[((long)b * C_ + row) * C_ + col] = acc[mi][nj][rr];
            }
}

// ---- stats: QF[bo] = H[bo,:].Weff[bo,:], MV[bo] = Weff[bo,:].r[b,:] ---------
__global__ __launch_bounds__(256) void stats_k(
    const float* __restrict__ H, const unsigned short* __restrict__ weh,
    const unsigned short* __restrict__ wel, const float* __restrict__ r,
    float* __restrict__ QF, float* __restrict__ MV)
{
    const int bo = blockIdx.x;           // 2048 = b*512+o
    const int b = bo >> 9;
    const float* Hr = H + (long)bo * C_;
    const unsigned short* wh = weh + (long)bo * C_;
    const unsigned short* wl = wel + (long)bo * C_;
    const float* rb = r + b * C_;
    const int t = threadIdx.x;
    float qf = 0.f, mv = 0.f;
    for (int j = t; j < C_; j += 256) {
        float ws = bf2f(wh[j]) + bf2f(wl[j]);
        qf += Hr[j] * ws;
        mv += ws * rb[j];
    }
    qf += __shfl_xor(qf, 1);  mv += __shfl_xor(mv, 1);
    qf += __shfl_xor(qf, 2);  mv += __shfl_xor(mv, 2);
    qf += __shfl_xor(qf, 4);  mv += __shfl_xor(mv, 4);
    qf += __shfl_xor(qf, 8);  mv += __shfl_xor(mv, 8);
    qf += __shfl_xor(qf, 16); mv += __shfl_xor(mv, 16);
    qf += __shfl_xor(qf, 32); mv += __shfl_xor(mv, 32);
    __shared__ float sq[4], sm[4];
    if ((t & 63) == 0) { sq[t >> 6] = qf; sm[t >> 6] = mv; }
    __syncthreads();
    if (t == 0) {
        QF[bo] = sq[0] + sq[1] + sq[2] + sq[3];
        MV[bo] = sm[0] + sm[1] + sm[2] + sm[3];
    }
}

// ---- finalize: sc, sh from analytic stats -----------------------------------
__global__ __launch_bounds__(512) void finalize_k(
    const float* __restrict__ QF, const float* __restrict__ MV,
    const float* __restrict__ be, const float* __restrict__ bw,
    const float* __restrict__ gamma, const float* __restrict__ beta,
    float* __restrict__ sc, float* __restrict__ sh)
{
    int o = threadIdx.x;
    float mean_acc = 0.f, ssq = 0.f;
    for (int b = 0; b < B_; ++b) {
        float bf = be[b * C_ + o] * (1.0f / (float)N_) + bw[o];
        float m = MV[b * C_ + o];
        float q = QF[b * C_ + o];
        mean_acc += m + (float)N_ * bf;
        ssq += q + 2.0f * bf * m + (float)N_ * bf * bf;
    }
    const float inv = 1.0f / ((float)B_ * (float)N_);
    float mean = mean_acc * inv;
    float var = ssq * inv - mean * mean;
    float s = gamma[o] * rsqrtf(var + 1e-5f);
    sc[o] = s;
    sh[o] = beta[o] - mean * s;
}

// ---- wy: out = ((Weh+Wel) Vth + bfull)*sc + sh + v. 128x128, BK=64 ----------
// grid (32, 4, 4)
__global__ __launch_bounds__(256, 2) void wy_mfma(
    const unsigned short* __restrict__ weh, const unsigned short* __restrict__ wel,
    const unsigned short* __restrict__ vth,
    const float* __restrict__ be, const float* __restrict__ bw,
    const float* __restrict__ sc, const float* __restrict__ sh,
    const float* __restrict__ v, float* __restrict__ out)
{
    __shared__ char smem[49152];    // Ah | Al | Bh
    const int t = threadIdx.x, lane = t & 63, w = t >> 6;
    const int b = blockIdx.z;
    const long m0 = blockIdx.y * 128;   // o
    const long n0 = blockIdx.x * 128;   // n
    const long S = (long)C_ * 2;        // 1024 B

    const char* wehb = (const char*)(weh + ((long)b * C_ + m0) * C_);
    const char* welb = (const char*)(wel + ((long)b * C_ + m0) * C_);
    const char* vhb  = (const char*)(vth + ((long)b * N_ + n0) * C_);
    char* AhL = smem; char* AlL = smem + 16384; char* BhL = smem + 32768;

    const char *g0, *g1; char *l0, *l1; int c0n;
    if (w == 0)      { g0 = wehb;          l0 = AhL;             c0n = 12; g1 = g0;   l1 = l0; }
    else if (w == 1) { g0 = wehb + 96 * S; l0 = AhL + 12 * 1024; c0n = 4;  g1 = welb; l1 = AlL; }
    else if (w == 2) { g0 = welb + 64 * S; l0 = AlL + 8 * 1024;  c0n = 8;  g1 = vhb;  l1 = BhL; }
    else             { g0 = vhb + 32 * S;  l0 = BhL + 4 * 1024;  c0n = 12; g1 = g0;   l1 = l0; }
    const long plane = (long)(lane >> 3) * S + (((lane & 7) ^ (lane >> 3)) << 4);

    const int wr = w >> 1, wc = w & 1;
    const int l15 = lane & 15, hi4 = lane >> 4;
    const int swz = (l15 & 7) << 4;
    const int arow = (wr * 64 + l15) * 128;
    const int brow = (wc * 64 + l15) * 128;

    f32x4 acc[4][4];
#pragma unroll
    for (int mi = 0; mi < 4; ++mi)
#pragma unroll
        for (int nj = 0; nj < 4; ++nj) acc[mi][nj] = (f32x4){0.f, 0.f, 0.f, 0.f};

    for (int s = 0; s < 8; ++s) {
#pragma unroll
        for (int i = 0; i < 12; ++i) {
            const char* src; char* dst;
            if (i < c0n) { src = g0 + (long)i * 8 * S;         dst = l0 + i * 1024; }
            else         { src = g1 + (long)(i - c0n) * 8 * S; dst = l1 + (i - c0n) * 1024; }
            gload_lds16(src + plane + s * 128, dst);
        }
        __syncthreads();
#pragma unroll
        for (int kk = 0; kk < 2; ++kk) {
            const int off = (kk * 64 + hi4 * 16) ^ swz;
            bf16x8 ah[4], al[4], bh[4];
#pragma unroll
            for (int mi = 0; mi < 4; ++mi) {
                ah[mi] = *(const bf16x8*)(AhL + arow + mi * 2048 + off);
                al[mi] = *(const bf16x8*)(AlL + arow + mi * 2048 + off);
            }
#pragma unroll
            for (int nj = 0; nj < 4; ++nj)
                bh[nj] = *(const bf16x8*)(BhL + brow + nj * 2048 + off);
#pragma unroll
            for (int mi = 0; mi < 4; ++mi)
#pragma unroll
                for (int nj = 0; nj < 4; ++nj)
                    acc[mi][nj] = __builtin_amdgcn_mfma_f32_16x16x32_bf16(ah[mi], bh[nj], acc[mi][nj], 0, 0, 0);
#pragma unroll
            for (int mi = 0; mi < 4; ++mi)
#pragma unroll
                for (int nj = 0; nj < 4; ++nj)
                    acc[mi][nj] = __builtin_amdgcn_mfma_f32_16x16x32_bf16(al[mi], bh[nj], acc[mi][nj], 0, 0, 0);
        }
        __syncthreads();
    }

#pragma unroll
    for (int mi = 0; mi < 4; ++mi) {
#pragma unroll
        for (int rr = 0; rr < 4; ++rr) {
            long o = m0 + wr * 64 + mi * 16 + hi4 * 4 + rr;
            float bf = be[b * C_ + o] * (1.0f / (float)N_) + bw[o];
            float s_c = sc[o], s_h = sh[o];
#pragma unroll
            for (int nj = 0; nj < 4; ++nj) {
                long n = n0 + wc * 64 + nj * 16 + l15;
                long e = ((long)b * C_ + o) * N_ + n;
                float val = acc[mi][nj][rr] + bf;
                out[e] = val * s_c + s_h + v[e];
            }
        }
    }
}

// ---- NN gemm 64x64 (fp32) with epilogues ------------------------------------
// mode 0: write C. mode 1: write C + beff atomic. mode 2: hi/lo bf16 cast.
__global__ __launch_bounds__(256) void gemm_nn(
    const float* __restrict__ A, long sA, int lda,
    const float* __restrict__ Bm, long sB, int ldb,
    float* __restrict__ Cm, long sC, int ldc,
    int K, float scale, int mode,
    const float* __restrict__ bth, float* __restrict__ be,
    unsigned short* __restrict__ weh, unsigned short* __restrict__ wel)
{
    int b = blockIdx.z;
    const float* Ab = A + (long)b * sA;
    const float* Bb = Bm + (long)b * sB;
    int i0 = blockIdx.y * 64, j0 = blockIdx.x * 64;

    __shared__ __align__(16) float As[16][64];
    __shared__ __align__(16) float Bs[16][64];

    int t = threadIdx.x, tx = t & 15, ty = t >> 4;
    int am = t >> 2, akq = (t & 3) << 2;
    int bk = t >> 4, bn4 = (t & 15) << 2;

    float acc[4][4];
#pragma unroll
    for (int r = 0; r < 4; ++r)
#pragma unroll
        for (int c = 0; c < 4; ++c) acc[r][c] = 0.f;

    for (int k0 = 0; k0 < K; k0 += 16) {
        float4 va = *(const float4*)&Ab[(long)(i0 + am) * lda + k0 + akq];
        As[akq + 0][am] = va.x; As[akq + 1][am] = va.y;
        As[akq + 2][am] = va.z; As[akq + 3][am] = va.w;
        *(float4*)&Bs[bk][bn4] = *(const float4*)&Bb[(long)(k0 + bk) * ldb + j0 + bn4];
        __syncthreads();
#pragma unroll
        for (int k = 0; k < 16; ++k) {
            float4 a4 = *(float4*)&As[k][ty * 4];
            float4 b4 = *(float4*)&Bs[k][tx * 4];
            float a[4]  = {a4.x, a4.y, a4.z, a4.w};
            float bb[4] = {b4.x, b4.y, b4.z, b4.w};
#pragma unroll
            for (int r = 0; r < 4; ++r)
#pragma unroll
                for (int c = 0; c < 4; ++c)
                    acc[r][c] += a[r] * bb[c];
        }
        __syncthreads();
    }

    if (mode == 2) {
#pragma unroll
        for (int r = 0; r < 4; ++r) {
            int o = i0 + ty * 4 + r, p = j0 + tx * 4;
            ushort4 h, l;
            float f0 = acc[r][0] * scale, f1 = acc[r][1] * scale;
            float f2 = acc[r][2] * scale, f3 = acc[r][3] * scale;
            h.x = f2bf(f0); l.x = f2bf(f0 - bf2f(h.x));
            h.y = f2bf(f1); l.y = f2bf(f1 - bf2f(h.y));
            h.z = f2bf(f2); l.z = f2bf(f2 - bf2f(h.z));
            h.w = f2bf(f3); l.w = f2bf(f3 - bf2f(h.w));
            long e = (((long)b * C_ + o) * C_ + p) >> 2;
            ((ushort4*)weh)[e] = h;
            ((ushort4*)wel)[e] = l;
        }
        return;
    }
    float* Cb = Cm + (long)b * sC;
#pragma unroll
    for (int r = 0; r < 4; ++r) {
        float4 o0 = make_float4(acc[r][0] * scale, acc[r][1] * scale,
                                acc[r][2] * scale, acc[r][3] * scale);
        *(float4*)&Cb[(long)(i0 + ty * 4 + r) * ldc + j0 + tx * 4] = o0;
    }
    if (mode == 1) {
#pragma unroll
        for (int r = 0; r < 4; ++r) {
            float pr = acc[r][0] * bth[j0 + tx * 4 + 0]
                     + acc[r][1] * bth[j0 + tx * 4 + 1]
                     + acc[r][2] * bth[j0 + tx * 4 + 2]
                     + acc[r][3] * bth[j0 + tx * 4 + 3];
            pr += __shfl_xor(pr, 1); pr += __shfl_xor(pr, 2);
            pr += __shfl_xor(pr, 4); pr += __shfl_xor(pr, 8);
            if (tx == 0) atomicAdd(&be[b * C_ + i0 + ty * 4 + r], pr);
        }
    }
}

// ---- SP (NT) = P1 Wph^T + rank-1 epilogue -----------------------------------
__global__ __launch_bounds__(256) void gemm_nt_sp(
    const float* __restrict__ P1, const float* __restrict__ Wph,
    float* __restrict__ SP, const float* __restrict__ u1,
    const float* __restrict__ u2, const float* __restrict__ bg,
    const float* __restrict__ bph)
{
    int b = blockIdx.z;
    const float* Ab = P1 + (long)b * (CI_ * C_);
    int i0 = blockIdx.y * 64, j0 = blockIdx.x * 64;

    __shared__ __align__(16) float As[16][64];
    __shared__ __align__(16) float Bs[16][64];

    int t = threadIdx.x, tx = t & 15, ty = t >> 4;
    int lr = t >> 2, lk = (t & 3) << 2;

    float acc[4][4];
#pragma unroll
    for (int r = 0; r < 4; ++r)
#pragma unroll
        for (int c = 0; c < 4; ++c) acc[r][c] = 0.f;

    for (int kt = 0; kt < C_; kt += 16) {
        float4 va = *(const float4*)&Ab[(long)(i0 + lr) * C_ + kt + lk];
        float4 vb = *(const float4*)&Wph[(long)(j0 + lr) * C_ + kt + lk];
        As[lk + 0][lr] = va.x; As[lk + 1][lr] = va.y; As[lk + 2][lr] = va.z; As[lk + 3][lr] = va.w;
        Bs[lk + 0][lr] = vb.x; Bs[lk + 1][lr] = vb.y; Bs[lk + 2][lr] = vb.z; Bs[lk + 3][lr] = vb.w;
        __syncthreads();
#pragma unroll
        for (int k = 0; k < 16; ++k) {
            float4 a4 = *(float4*)&As[k][ty * 4];
            float4 b4 = *(float4*)&Bs[k][tx * 4];
            float a[4]  = {a4.x, a4.y, a4.z, a4.w};
            float bb[4] = {b4.x, b4.y, b4.z, b4.w};
#pragma unroll
            for (int r = 0; r < 4; ++r)
#pragma unroll
                for (int c = 0; c < 4; ++c)
                    acc[r][c] += a[r] * bb[c];
        }
        __syncthreads();
    }
    float* Cb = SP + (long)b * (CI_ * CI_);
#pragma unroll
    for (int r = 0; r < 4; ++r) {
        int cr = i0 + ty * 4 + r;
        float u1v = u1[b * CI_ + cr], bgv = bg[cr];
        float4 o0;
        float* po = (float*)&o0;
#pragma unroll
        for (int c = 0; c < 4; ++c) {
            int ic = j0 + tx * 4 + c;
            po[c] = acc[r][c] + u1v * bph[ic] + bgv * (u2[b * CI_ + ic] + (float)N_ * bph[ic]);
        }
        *(float4*)&Cb[(long)cr * CI_ + j0 + tx * 4] = o0;
    }
}

// ---- rank1_prep: u1 = Wg r, u2 = Wph r --------------------------------------
__global__ __launch_bounds__(256) void rank1_prep(
    const float* __restrict__ Wg, const float* __restrict__ Wph,
    const float* __restrict__ r, float* __restrict__ u1, float* __restrict__ u2)
{
    int blk = blockIdx.x;
    int b = blk >> 2, q = blk & 3;
    int t = threadIdx.x;
    int c = q * 64 + (t >> 2);
    int kq = t & 3;
    const float* rb = r + b * C_;
    float s1 = 0.f, s2 = 0.f;
    for (int k = kq * 128; k < kq * 128 + 128; k += 4) {
        float4 wg = *(const float4*)&Wg[(long)c * C_ + k];
        float4 wp = *(const float4*)&Wph[(long)c * C_ + k];
        float4 rv = *(const float4*)&rb[k];
        s1 += wg.x * rv.x + wg.y * rv.y + wg.z * rv.z + wg.w * rv.w;
        s2 += wp.x * rv.x + wp.y * rv.y + wp.z * rv.z + wp.w * rv.w;
    }
    s1 += __shfl_xor(s1, 1); s2 += __shfl_xor(s2, 1);
    s1 += __shfl_xor(s1, 2); s2 += __shfl_xor(s2, 2);
    if (kq == 0) {
        u1[b * CI_ + c] = s1;
        u2[b * CI_ + c] = s2;
    }
}

// ---- launch -----------------------------------------------------------------
extern "C" void kernel_launch(void* const* d_in, const int* in_sizes, int n_in,
                              void* d_out, int out_size, void* d_ws, size_t ws_size,
                              hipStream_t stream)
{
    const float* v     = (const float*)d_in[0];
    const float* Wg    = (const float*)d_in[1];
    const float* bg    = (const float*)d_in[2];
    const float* Wth   = (const float*)d_in[3];
    const float* bth   = (const float*)d_in[4];
    const float* Wph   = (const float*)d_in[5];
    const float* bph   = (const float*)d_in[6];
    const float* Ww    = (const float*)d_in[7];
    const float* bw    = (const float*)d_in[8];
    const float* gamma = (const float*)d_in[9];
    const float* beta  = (const float*)d_in[10];
    float* out = (float*)d_out;
    float* ws  = (float*)d_ws;

    float* G    = ws + G_OFF;
    float* H    = ws + H_OFF;
    float* P1   = ws + P1_OFF;
    float* SP   = ws + SP_OFF;
    float* P2   = ws + P2_OFF;
    float* r    = ws + R_OFF;
    float* be   = ws + BE_OFF;
    float* u1   = ws + U1_OFF;
    float* u2   = ws + U2_OFF;
    float* QF   = ws + QF_OFF;
    float* MV   = ws + MV_OFF;
    float* sc   = ws + SC_OFF;
    float* sh   = ws + SH_OFF;
    unsigned short* Gh  = (unsigned short*)(ws + GH_OFF);
    unsigned short* vh  = (unsigned short*)(ws + VH_OFF);
    unsigned short* vl  = (unsigned short*)(ws + VL_OFF);
    unsigned short* vth = (unsigned short*)(ws + VTH_OFF);
    unsigned short* weh = (unsigned short*)(ws + WEH_OFF);
    unsigned short* wel = (unsigned short*)(ws + WEL_OFF);

    // zero atomic targets: G, and misc r+be (contiguous 4096 floats)
    hipMemsetAsync(G, 0, 1048576 * sizeof(float), stream);
    hipMemsetAsync(r, 0, 4096 * sizeof(float), stream);

    // v -> vh, vl, vth, rowsums
    cast_fused<<<dim3(64, 8, 4), 256, 0, stream>>>(v, vh, vl, vth, r);

    // G lower-triangle (split-K=16), then mirror
    gram_mfma<<<dim3(10, 1, 64), 256, 0, stream>>>(vh, vl, G);
    mirror_g<<<dim3(8, 8, 4), 256, 0, stream>>>(G);

    // u1 = Wg r, u2 = Wph r
    rank1_prep<<<16, 256, 0, stream>>>(Wg, Wph, r, u1, u2);

    // P1 = Wg G
    gemm_nn<<<dim3(8, 4, 4), 256, 0, stream>>>(
        Wg, 0, C_, G, (long)C_ * C_, C_, P1, (long)CI_ * C_, C_,
        C_, 1.0f, 0, nullptr, nullptr, nullptr, nullptr);

    // S' = P1 Wph^T + rank-1
    gemm_nt_sp<<<dim3(4, 4, 4), 256, 0, stream>>>(P1, Wph, SP, u1, u2, bg, bph);

    // P2 = Ww S' + be atomics
    gemm_nn<<<dim3(4, 8, 4), 256, 0, stream>>>(
        Ww, 0, CI_, SP, (long)CI_ * CI_, CI_, P2, (long)C_ * CI_, CI_,
        CI_, 1.0f, 1, bth, be, nullptr, nullptr);

    // Weff = (1/N) P2 Wth -> bf16 hi/lo
    gemm_nn<<<dim3(8, 8, 4), 256, 0, stream>>>(
        P2, (long)C_ * CI_, CI_, Wth, 0, C_, nullptr, 0, 0,
        CI_, 1.0f / (float)N_, 2, nullptr, nullptr, weh, wel);

    // analytic BN stats: H = Weff G ; QF/MV ; sc,sh
    g_cast<<<1024, 256, 0, stream>>>(G, Gh);
    h_mfma<<<dim3(4, 4, 4), 256, 0, stream>>>(weh, wel, Gh, H);
    stats_k<<<2048, 256, 0, stream>>>(H, weh, wel, r, QF, MV);
    finalize_k<<<1, 512, 0, stream>>>(QF, MV, be, bw, gamma, beta, sc, sh);

    // Wy with fused BN apply + residual
    wy_mfma<<<dim3(32, 4, 4), 256, 0, stream>>>(weh, wel, vth, be, bw, sc, sh, v, out);
}

// Round 7
// 288.263 us; speedup vs baseline: 1.1959x; 1.0749x over previous
//
#include <hip/hip_runtime.h>
#include <math.h>

// Rs_GCN, round 7: round 6 with gram atomics -> streaming split-K partials
// (round-6 PMC: gram MfmaUtil 7.9%, WRITE 41MB = 10.5M contended device atomics).
// gram writes Gp partials; new reduce_mirror sums 8 partials and writes
// G fp32 (both triangles) + Gh bf16 (both) -- fuses mirror_g + g_cast.
//   G[b] = Vh (Vh+Vl)^T   (lower tiles, split-K=8 partials) -> reduce_mirror
//   S'   = Wg G Wph^T + u1 bph^T + bg u2^T + N bg bph^T
//   Weff = (1/N) Ww S' Wth (-> bf16 hi/lo) ; be = Ww S' bth (atomic)
//   H    = (Weh+Wel) Gh ; QF/MV -> sc,sh   (analytic BN stats)
//   out  = ((Weh+Wel) Vth + bfull)*sc + sh + v

#define B_  4
#define C_  512
#define CI_ 256
#define N_  4096

typedef __attribute__((ext_vector_type(8))) short bf16x8;
typedef __attribute__((ext_vector_type(4))) float f32x4;

// ---- ws float offsets -------------------------------------------------------
#define G_OFF     0L          // 1,048,576  [B][512][512] fp32
#define GH_OFF    1048576L    //   524,288  (1,048,576 ushort)
#define H_OFF     1572864L    // 1,048,576
#define P1_OFF    2621440L    //   524,288
#define SP_OFF    3145728L    //   262,144
#define P2_OFF    3407872L    //   524,288
#define MISC_OFF  3932160L    //    12,288 reserved
#define R_OFF     (MISC_OFF + 0)      // 2048
#define BE_OFF    (MISC_OFF + 2048)   // 2048
#define U1_OFF    (MISC_OFF + 4096)   // 1024
#define U2_OFF    (MISC_OFF + 5120)   // 1024
#define QF_OFF    (MISC_OFF + 6144)   // 2048
#define MV_OFF    (MISC_OFF + 8192)   // 2048
#define SC_OFF    (MISC_OFF + 10240)  //  512
#define SH_OFF    (MISC_OFF + 10752)  //  512
#define VH_OFF    3944448L    // 4,194,304 (8,388,608 ushort)
#define VL_OFF    8138752L
#define VTH_OFF   12333056L
#define WEH_OFF   16527360L   //   524,288 (1,048,576 ushort)
#define WEL_OFF   17051648L   //   524,288
#define GP_OFF    17575936L   // 5,242,880  [b][tile10][ch8][128][128]
// total 22,818,816 floats ~= 91.3 MB

// ---- helpers ----------------------------------------------------------------
__device__ __forceinline__ unsigned short f2bf(float f) {
    union { float f; unsigned int u; } a; a.f = f;
    unsigned int u = a.u;
    u += 0x7fffu + ((u >> 16) & 1u);      // round-to-nearest-even
    return (unsigned short)(u >> 16);
}
__device__ __forceinline__ float bf2f(unsigned short s) {
    union { unsigned int u; float f; } a; a.u = ((unsigned int)s) << 16; return a.f;
}
__device__ __forceinline__ void gload_lds16(const char* g, char* l) {
    __builtin_amdgcn_global_load_lds(
        (const __attribute__((address_space(1))) unsigned int*)g,
        (__attribute__((address_space(3))) unsigned int*)l, 16, 0, 0);
}

// ---- fused cast: v -> vh,vl ([B][C][N]), vth ([B][N][C]), rowsums r ---------
__global__ __launch_bounds__(256) void cast_fused(
    const float* __restrict__ v, unsigned short* __restrict__ vh,
    unsigned short* __restrict__ vl, unsigned short* __restrict__ vth,
    float* __restrict__ r)
{
    __shared__ float tile[64][65];
    const int b = blockIdx.z;
    const int n0 = blockIdx.x * 64, c0 = blockIdx.y * 64;
    const int t = threadIdx.x, rq = t >> 4, cq = t & 15;
#pragma unroll
    for (int p = 0; p < 4; ++p) {
        int row = p * 16 + rq;
        long e = ((long)(b * C_ + c0 + row)) * N_ + n0 + cq * 4;
        float4 f = *(const float4*)&v[e];
        ushort4 h, l;
        h.x = f2bf(f.x); l.x = f2bf(f.x - bf2f(h.x));
        h.y = f2bf(f.y); l.y = f2bf(f.y - bf2f(h.y));
        h.z = f2bf(f.z); l.z = f2bf(f.z - bf2f(h.z));
        h.w = f2bf(f.w); l.w = f2bf(f.w - bf2f(h.w));
        *(ushort4*)&vh[e] = h;
        *(ushort4*)&vl[e] = l;
        tile[row][cq * 4 + 0] = f.x; tile[row][cq * 4 + 1] = f.y;
        tile[row][cq * 4 + 2] = f.z; tile[row][cq * 4 + 3] = f.w;
        float s = f.x + f.y + f.z + f.w;
        s += __shfl_xor(s, 1); s += __shfl_xor(s, 2);
        s += __shfl_xor(s, 4); s += __shfl_xor(s, 8);
        if (cq == 0) atomicAdd(&r[b * C_ + c0 + row], s);
    }
    __syncthreads();
#pragma unroll
    for (int p = 0; p < 4; ++p) {
        int nl = p * 16 + rq;
        float f0 = tile[cq * 4 + 0][nl], f1 = tile[cq * 4 + 1][nl];
        float f2 = tile[cq * 4 + 2][nl], f3 = tile[cq * 4 + 3][nl];
        ushort4 h;
        h.x = f2bf(f0); h.y = f2bf(f1); h.z = f2bf(f2); h.w = f2bf(f3);
        long e = ((long)(b * N_ + n0 + nl)) * C_ + c0 + cq * 4;
        *(ushort4*)&vth[e] = h;
    }
}

// ---- gram: lower-triangle 128x128 tiles, 2-term, split-K=8, partials --------
// grid (10, 1, 32): x = tile pair, z = b*8+ch (chunk of 512 K-elems, 8 s-steps)
__global__ __launch_bounds__(256, 2) void gram_mfma(
    const unsigned short* __restrict__ vh, const unsigned short* __restrict__ vl,
    float* __restrict__ Gp)
{
    __shared__ char smem[49152];    // Ah 16K | Bh 16K | Bl 16K
    const int MT[10] = {0,1,1,2,2,2,3,3,3,3};
    const int NT[10] = {0,0,1,0,1,2,0,1,2,3};
    const int t = threadIdx.x, lane = t & 63, w = t >> 6;
    const int z = blockIdx.z, b = z >> 3, ch = z & 7;
    const long m0 = MT[blockIdx.x] * 128, n0 = NT[blockIdx.x] * 128;
    const long k0b = (long)ch * 1024;                  // 512 elems * 2B
    const long stride = (long)N_ * 2;                  // 8192 B

    const char* vhm = (const char*)(vh + ((long)b * C_ + m0) * N_) + k0b;
    const char* vhn = (const char*)(vh + ((long)b * C_ + n0) * N_) + k0b;
    const char* vln = (const char*)(vl + ((long)b * C_ + n0) * N_) + k0b;
    char* AhL = smem; char* BhL = smem + 16384; char* BlL = smem + 32768;

    const char *g0, *g1; char *l0, *l1; int c0n;
    if (w == 0)      { g0 = vhm;                l0 = AhL;             c0n = 12; g1 = g0;  l1 = l0; }
    else if (w == 1) { g0 = vhm + 96 * stride;  l0 = AhL + 12 * 1024; c0n = 4;  g1 = vhn; l1 = BhL; }
    else if (w == 2) { g0 = vhn + 64 * stride;  l0 = BhL + 8 * 1024;  c0n = 8;  g1 = vln; l1 = BlL; }
    else             { g0 = vln + 32 * stride;  l0 = BlL + 4 * 1024;  c0n = 12; g1 = g0;  l1 = l0; }
    const long plane = (long)(lane >> 3) * stride + (((lane & 7) ^ (lane >> 3)) << 4);

    const int wr = w >> 1, wc = w & 1;
    const int l15 = lane & 15, hi4 = lane >> 4;
    const int swz = (l15 & 7) << 4;
    const int arow = (wr * 64 + l15) * 128;
    const int brow = (wc * 64 + l15) * 128;

    f32x4 acc[4][4];
#pragma unroll
    for (int mi = 0; mi < 4; ++mi)
#pragma unroll
        for (int nj = 0; nj < 4; ++nj) acc[mi][nj] = (f32x4){0.f, 0.f, 0.f, 0.f};

    for (int s = 0; s < 8; ++s) {
#pragma unroll
        for (int i = 0; i < 12; ++i) {
            const char* src; char* dst;
            if (i < c0n) { src = g0 + (long)i * 8 * stride;         dst = l0 + i * 1024; }
            else         { src = g1 + (long)(i - c0n) * 8 * stride; dst = l1 + (i - c0n) * 1024; }
            gload_lds16(src + plane + s * 128, dst);
        }
        __syncthreads();
#pragma unroll
        for (int kk = 0; kk < 2; ++kk) {
            const int off = (kk * 64 + hi4 * 16) ^ swz;
            bf16x8 ah[4], bh[4], bl[4];
#pragma unroll
            for (int mi = 0; mi < 4; ++mi)
                ah[mi] = *(const bf16x8*)(AhL + arow + mi * 2048 + off);
#pragma unroll
            for (int nj = 0; nj < 4; ++nj) {
                bh[nj] = *(const bf16x8*)(BhL + brow + nj * 2048 + off);
                bl[nj] = *(const bf16x8*)(BlL + brow + nj * 2048 + off);
            }
#pragma unroll
            for (int mi = 0; mi < 4; ++mi)
#pragma unroll
                for (int nj = 0; nj < 4; ++nj)
                    acc[mi][nj] = __builtin_amdgcn_mfma_f32_16x16x32_bf16(ah[mi], bh[nj], acc[mi][nj], 0, 0, 0);
#pragma unroll
            for (int mi = 0; mi < 4; ++mi)
#pragma unroll
                for (int nj = 0; nj < 4; ++nj)
                    acc[mi][nj] = __builtin_amdgcn_mfma_f32_16x16x32_bf16(ah[mi], bl[nj], acc[mi][nj], 0, 0, 0);
        }
        __syncthreads();
    }
    // streaming partial store (no atomics)
    float* gp = Gp + (((long)b * 10 + blockIdx.x) * 8 + ch) * 16384;
#pragma unroll
    for (int mi = 0; mi < 4; ++mi)
#pragma unroll
        for (int nj = 0; nj < 4; ++nj)
#pragma unroll
            for (int rr = 0; rr < 4; ++rr) {
                int row = wr * 64 + mi * 16 + hi4 * 4 + rr;
                int col = wc * 64 + nj * 16 + l15;
                gp[row * 128 + col] = acc[mi][nj][rr];
            }
}

// ---- reduce_mirror: sum 8 partials -> G fp32 (both tri) + Gh bf16 (both) ----
// grid (4 strips, 10 tiles, 4 b), 256 threads; each strip = 32 cols.
__global__ __launch_bounds__(256) void reduce_mirror(
    const float* __restrict__ Gp, float* __restrict__ G,
    unsigned short* __restrict__ Gh)
{
    const int MT[10] = {0,1,1,2,2,2,3,3,3,3};
    const int NT[10] = {0,0,1,0,1,2,0,1,2,3};
    const int strip = blockIdx.x, x = blockIdx.y, b = blockIdx.z;
    const int I = MT[x], J = NT[x];
    const float* base = Gp + ((long)(b * 10 + x) * 8) * 16384;
    float* Gb = G + (long)b * C_ * C_;
    unsigned short* Ghb = Gh + (long)b * C_ * C_;
    const int t = threadIdx.x;
    const int c = strip * 32 + (t & 7) * 4;   // local col
    const int r0 = t >> 3;                    // 0..31
#pragma unroll
    for (int rp = 0; rp < 4; ++rp) {
        int row = rp * 32 + r0;
        float4 s = make_float4(0.f, 0.f, 0.f, 0.f);
#pragma unroll
        for (int ch = 0; ch < 8; ++ch) {
            float4 p = *(const float4*)&base[ch * 16384 + row * 128 + c];
            s.x += p.x; s.y += p.y; s.z += p.z; s.w += p.w;
        }
        long rg = I * 128 + row, cg = J * 128 + c;
        ushort4 h;
        h.x = f2bf(s.x); h.y = f2bf(s.y); h.z = f2bf(s.z); h.w = f2bf(s.w);
        if (I != J) {
            *(float4*)&Gb[rg * C_ + cg]   = s;
            *(ushort4*)&Ghb[rg * C_ + cg] = h;
            const float sv[4] = {s.x, s.y, s.z, s.w};
            const unsigned short hv[4] = {h.x, h.y, h.z, h.w};
#pragma unroll
            for (int j = 0; j < 4; ++j) {
                Gb[(cg + j) * C_ + rg]  = sv[j];
                Ghb[(cg + j) * C_ + rg] = hv[j];
            }
        } else {
            const float sv[4] = {s.x, s.y, s.z, s.w};
            const unsigned short hv[4] = {h.x, h.y, h.z, h.w};
#pragma unroll
            for (int j = 0; j < 4; ++j) {
                if (c + j <= row) {       // primary (lower incl. diag) + mirror
                    Gb[rg * C_ + cg + j]    = sv[j];
                    Ghb[rg * C_ + cg + j]   = hv[j];
                    Gb[(cg + j) * C_ + rg]  = sv[j];
                    Ghb[(cg + j) * C_ + rg] = hv[j];
                }
            }
        }
    }
}

// ---- h_mfma: H[b] = (Weh+Wel) Gh   (G symmetric -> rows as B-operand) -------
__global__ __launch_bounds__(256, 2) void h_mfma(
    const unsigned short* __restrict__ weh, const unsigned short* __restrict__ wel,
    const unsigned short* __restrict__ Gh, float* __restrict__ H)
{
    __shared__ char smem[49152];    // Ah | Al | Bh
    const int t = threadIdx.x, lane = t & 63, w = t >> 6;
    const int b = blockIdx.z;
    const long m0 = blockIdx.y * 128, n0 = blockIdx.x * 128;
    const long S = (long)C_ * 2;

    const char* wehb = (const char*)(weh + ((long)b * C_ + m0) * C_);
    const char* welb = (const char*)(wel + ((long)b * C_ + m0) * C_);
    const char* ghb  = (const char*)(Gh  + ((long)b * C_ + n0) * C_);
    char* AhL = smem; char* AlL = smem + 16384; char* BhL = smem + 32768;

    const char *g0, *g1; char *l0, *l1; int c0n;
    if (w == 0)      { g0 = wehb;          l0 = AhL;             c0n = 12; g1 = g0;   l1 = l0; }
    else if (w == 1) { g0 = wehb + 96 * S; l0 = AhL + 12 * 1024; c0n = 4;  g1 = welb; l1 = AlL; }
    else if (w == 2) { g0 = welb + 64 * S; l0 = AlL + 8 * 1024;  c0n = 8;  g1 = ghb;  l1 = BhL; }
    else             { g0 = ghb + 32 * S;  l0 = BhL + 4 * 1024;  c0n = 12; g1 = g0;   l1 = l0; }
    const long plane = (long)(lane >> 3) * S + (((lane & 7) ^ (lane >> 3)) << 4);

    const int wr = w >> 1, wc = w & 1;
    const int l15 = lane & 15, hi4 = lane >> 4;
    const int swz = (l15 & 7) << 4;
    const int arow = (wr * 64 + l15) * 128;
    const int brow = (wc * 64 + l15) * 128;

    f32x4 acc[4][4];
#pragma unroll
    for (int mi = 0; mi < 4; ++mi)
#pragma unroll
        for (int nj = 0; nj < 4; ++nj) acc[mi][nj] = (f32x4){0.f, 0.f, 0.f, 0.f};

    for (int s = 0; s < 8; ++s) {
#pragma unroll
        for (int i = 0; i < 12; ++i) {
            const char* src; char* dst;
            if (i < c0n) { src = g0 + (long)i * 8 * S;         dst = l0 + i * 1024; }
            else         { src = g1 + (long)(i - c0n) * 8 * S; dst = l1 + (i - c0n) * 1024; }
            gload_lds16(src + plane + s * 128, dst);
        }
        __syncthreads();
#pragma unroll
        for (int kk = 0; kk < 2; ++kk) {
            const int off = (kk * 64 + hi4 * 16) ^ swz;
            bf16x8 ah[4], al[4], bh[4];
#pragma unroll
            for (int mi = 0; mi < 4; ++mi) {
                ah[mi] = *(const bf16x8*)(AhL + arow + mi * 2048 + off);
                al[mi] = *(const bf16x8*)(AlL + arow + mi * 2048 + off);
            }
#pragma unroll
            for (int nj = 0; nj < 4; ++nj)
                bh[nj] = *(const bf16x8*)(BhL + brow + nj * 2048 + off);
#pragma unroll
            for (int mi = 0; mi < 4; ++mi)
#pragma unroll
                for (int nj = 0; nj < 4; ++nj)
                    acc[mi][nj] = __builtin_amdgcn_mfma_f32_16x16x32_bf16(ah[mi], bh[nj], acc[mi][nj], 0, 0, 0);
#pragma unroll
            for (int mi = 0; mi < 4; ++mi)
#pragma unroll
                for (int nj = 0; nj < 4; ++nj)
                    acc[mi][nj] = __builtin_amdgcn_mfma_f32_16x16x32_bf16(al[mi], bh[nj], acc[mi][nj], 0, 0, 0);
        }
        __syncthreads();
    }
#pragma unroll
    for (int mi = 0; mi < 4; ++mi)
#pragma unroll
        for (int nj = 0; nj < 4; ++nj)
#pragma unroll
            for (int rr = 0; rr < 4; ++rr) {
                long row = m0 + wr * 64 + mi * 16 + hi4 * 4 + rr;
                long col = n0 + wc * 64 + nj * 16 + l15;
                H[((long)b * C_ + row) * C_ + col] = acc[mi][nj][rr];
            }
}

// ---- stats: QF[bo] = H[bo,:].Weff[bo,:], MV[bo] = Weff[bo,:].r[b,:] ---------
__global__ __launch_bounds__(256) void stats_k(
    const float* __restrict__ H, const unsigned short* __restrict__ weh,
    const unsigned short* __restrict__ wel, const float* __restrict__ r,
    float* __restrict__ QF, float* __restrict__ MV)
{
    const int bo = blockIdx.x;
    const int b = bo >> 9;
    const float* Hr = H + (long)bo * C_;
    const unsigned short* wh = weh + (long)bo * C_;
    const unsigned short* wl = wel + (long)bo * C_;
    const float* rb = r + b * C_;
    const int t = threadIdx.x;
    float qf = 0.f, mv = 0.f;
    for (int j = t; j < C_; j += 256) {
        float ws = bf2f(wh[j]) + bf2f(wl[j]);
        qf += Hr[j] * ws;
        mv += ws * rb[j];
    }
    qf += __shfl_xor(qf, 1);  mv += __shfl_xor(mv, 1);
    qf += __shfl_xor(qf, 2);  mv += __shfl_xor(mv, 2);
    qf += __shfl_xor(qf, 4);  mv += __shfl_xor(mv, 4);
    qf += __shfl_xor(qf, 8);  mv += __shfl_xor(mv, 8);
    qf += __shfl_xor(qf, 16); mv += __shfl_xor(mv, 16);
    qf += __shfl_xor(qf, 32); mv += __shfl_xor(mv, 32);
    __shared__ float sq[4], sm[4];
    if ((t & 63) == 0) { sq[t >> 6] = qf; sm[t >> 6] = mv; }
    __syncthreads();
    if (t == 0) {
        QF[bo] = sq[0] + sq[1] + sq[2] + sq[3];
        MV[bo] = sm[0] + sm[1] + sm[2] + sm[3];
    }
}

// ---- finalize: sc, sh from analytic stats -----------------------------------
__global__ __launch_bounds__(512) void finalize_k(
    const float* __restrict__ QF, const float* __restrict__ MV,
    const float* __restrict__ be, const float* __restrict__ bw,
    const float* __restrict__ gamma, const float* __restrict__ beta,
    float* __restrict__ sc, float* __restrict__ sh)
{
    int o = threadIdx.x;
    float mean_acc = 0.f, ssq = 0.f;
    for (int b = 0; b < B_; ++b) {
        float bf = be[b * C_ + o] * (1.0f / (float)N_) + bw[o];
        float m = MV[b * C_ + o];
        float q = QF[b * C_ + o];
        mean_acc += m + (float)N_ * bf;
        ssq += q + 2.0f * bf * m + (float)N_ * bf * bf;
    }
    const float inv = 1.0f / ((float)B_ * (float)N_);
    float mean = mean_acc * inv;
    float var = ssq * inv - mean * mean;
    float s = gamma[o] * rsqrtf(var + 1e-5f);
    sc[o] = s;
    sh[o] = beta[o] - mean * s;
}

// ---- wy: out = ((Weh+Wel) Vth + bfull)*sc + sh + v. 128x128, BK=64 ----------
__global__ __launch_bounds__(256, 2) void wy_mfma(
    const unsigned short* __restrict__ weh, const unsigned short* __restrict__ wel,
    const unsigned short* __restrict__ vth,
    const float* __restrict__ be, const float* __restrict__ bw,
    const float* __restrict__ sc, const float* __restrict__ sh,
    const float* __restrict__ v, float* __restrict__ out)
{
    __shared__ char smem[49152];    // Ah | Al | Bh
    const int t = threadIdx.x, lane = t & 63, w = t >> 6;
    const int b = blockIdx.z;
    const long m0 = blockIdx.y * 128;
    const long n0 = blockIdx.x * 128;
    const long S = (long)C_ * 2;

    const char* wehb = (const char*)(weh + ((long)b * C_ + m0) * C_);
    const char* welb = (const char*)(wel + ((long)b * C_ + m0) * C_);
    const char* vhb  = (const char*)(vth + ((long)b * N_ + n0) * C_);
    char* AhL = smem; char* AlL = smem + 16384; char* BhL = smem + 32768;

    const char *g0, *g1; char *l0, *l1; int c0n;
    if (w == 0)      { g0 = wehb;          l0 = AhL;             c0n = 12; g1 = g0;   l1 = l0; }
    else if (w == 1) { g0 = wehb + 96 * S; l0 = AhL + 12 * 1024; c0n = 4;  g1 = welb; l1 = AlL; }
    else if (w == 2) { g0 = welb + 64 * S; l0 = AlL + 8 * 1024;  c0n = 8;  g1 = vhb;  l1 = BhL; }
    else             { g0 = vhb + 32 * S;  l0 = BhL + 4 * 1024;  c0n = 12; g1 = g0;   l1 = l0; }
    const long plane = (long)(lane >> 3) * S + (((lane & 7) ^ (lane >> 3)) << 4);

    const int wr = w >> 1, wc = w & 1;
    const int l15 = lane & 15, hi4 = lane >> 4;
    const int swz = (l15 & 7) << 4;
    const int arow = (wr * 64 + l15) * 128;
    const int brow = (wc * 64 + l15) * 128;

    f32x4 acc[4][4];
#pragma unroll
    for (int mi = 0; mi < 4; ++mi)
#pragma unroll
        for (int nj = 0; nj < 4; ++nj) acc[mi][nj] = (f32x4){0.f, 0.f, 0.f, 0.f};

    for (int s = 0; s < 8; ++s) {
#pragma unroll
        for (int i = 0; i < 12; ++i) {
            const char* src; char* dst;
            if (i < c0n) { src = g0 + (long)i * 8 * S;         dst = l0 + i * 1024; }
            else         { src = g1 + (long)(i - c0n) * 8 * S; dst = l1 + (i - c0n) * 1024; }
            gload_lds16(src + plane + s * 128, dst);
        }
        __syncthreads();
#pragma unroll
        for (int kk = 0; kk < 2; ++kk) {
            const int off = (kk * 64 + hi4 * 16) ^ swz;
            bf16x8 ah[4], al[4], bh[4];
#pragma unroll
            for (int mi = 0; mi < 4; ++mi) {
                ah[mi] = *(const bf16x8*)(AhL + arow + mi * 2048 + off);
                al[mi] = *(const bf16x8*)(AlL + arow + mi * 2048 + off);
            }
#pragma unroll
            for (int nj = 0; nj < 4; ++nj)
                bh[nj] = *(const bf16x8*)(BhL + brow + nj * 2048 + off);
#pragma unroll
            for (int mi = 0; mi < 4; ++mi)
#pragma unroll
                for (int nj = 0; nj < 4; ++nj)
                    acc[mi][nj] = __builtin_amdgcn_mfma_f32_16x16x32_bf16(ah[mi], bh[nj], acc[mi][nj], 0, 0, 0);
#pragma unroll
            for (int mi = 0; mi < 4; ++mi)
#pragma unroll
                for (int nj = 0; nj < 4; ++nj)
                    acc[mi][nj] = __builtin_amdgcn_mfma_f32_16x16x32_bf16(al[mi], bh[nj], acc[mi][nj], 0, 0, 0);
        }
        __syncthreads();
    }

#pragma unroll
    for (int mi = 0; mi < 4; ++mi) {
#pragma unroll
        for (int rr = 0; rr < 4; ++rr) {
            long o = m0 + wr * 64 + mi * 16 + hi4 * 4 + rr;
            float bf = be[b * C_ + o] * (1.0f / (float)N_) + bw[o];
            float s_c = sc[o], s_h = sh[o];
#pragma unroll
            for (int nj = 0; nj < 4; ++nj) {
                long n = n0 + wc * 64 + nj * 16 + l15;
                long e = ((long)b * C_ + o) * N_ + n;
                float val = acc[mi][nj][rr] + bf;
                out[e] = val * s_c + s_h + v[e];
            }
        }
    }
}

// ---- NN gemm 64x64 (fp32) with epilogues ------------------------------------
// mode 0: write C. mode 1: write C + beff atomic. mode 2: hi/lo bf16 cast.
__global__ __launch_bounds__(256) void gemm_nn(
    const float* __restrict__ A, long sA, int lda,
    const float* __restrict__ Bm, long sB, int ldb,
    float* __restrict__ Cm, long sC, int ldc,
    int K, float scale, int mode,
    const float* __restrict__ bth, float* __restrict__ be,
    unsigned short* __restrict__ weh, unsigned short* __restrict__ wel)
{
    int b = blockIdx.z;
    const float* Ab = A + (long)b * sA;
    const float* Bb = Bm + (long)b * sB;
    int i0 = blockIdx.y * 64, j0 = blockIdx.x * 64;

    __shared__ __align__(16) float As[16][64];
    __shared__ __align__(16) float Bs[16][64];

    int t = threadIdx.x, tx = t & 15, ty = t >> 4;
    int am = t >> 2, akq = (t & 3) << 2;
    int bk = t >> 4, bn4 = (t & 15) << 2;

    float acc[4][4];
#pragma unroll
    for (int r = 0; r < 4; ++r)
#pragma unroll
        for (int c = 0; c < 4; ++c) acc[r][c] = 0.f;

    for (int k0 = 0; k0 < K; k0 += 16) {
        float4 va = *(const float4*)&Ab[(long)(i0 + am) * lda + k0 + akq];
        As[akq + 0][am] = va.x; As[akq + 1][am] = va.y;
        As[akq + 2][am] = va.z; As[akq + 3][am] = va.w;
        *(float4*)&Bs[bk][bn4] = *(const float4*)&Bb[(long)(k0 + bk) * ldb + j0 + bn4];
        __syncthreads();
#pragma unroll
        for (int k = 0; k < 16; ++k) {
            float4 a4 = *(float4*)&As[k][ty * 4];
            float4 b4 = *(float4*)&Bs[k][tx * 4];
            float a[4]  = {a4.x, a4.y, a4.z, a4.w};
            float bb[4] = {b4.x, b4.y, b4.z, b4.w};
#pragma unroll
            for (int r = 0; r < 4; ++r)
#pragma unroll
                for (int c = 0; c < 4; ++c)
                    acc[r][c] += a[r] * bb[c];
        }
        __syncthreads();
    }

    if (mode == 2) {
#pragma unroll
        for (int r = 0; r < 4; ++r) {
            int o = i0 + ty * 4 + r, p = j0 + tx * 4;
            ushort4 h, l;
            float f0 = acc[r][0] * scale, f1 = acc[r][1] * scale;
            float f2 = acc[r][2] * scale, f3 = acc[r][3] * scale;
            h.x = f2bf(f0); l.x = f2bf(f0 - bf2f(h.x));
            h.y = f2bf(f1); l.y = f2bf(f1 - bf2f(h.y));
            h.z = f2bf(f2); l.z = f2bf(f2 - bf2f(h.z));
            h.w = f2bf(f3); l.w = f2bf(f3 - bf2f(h.w));
            long e = (((long)b * C_ + o) * C_ + p) >> 2;
            ((ushort4*)weh)[e] = h;
            ((ushort4*)wel)[e] = l;
        }
        return;
    }
    float* Cb = Cm + (long)b * sC;
#pragma unroll
    for (int r = 0; r < 4; ++r) {
        float4 o0 = make_float4(acc[r][0] * scale, acc[r][1] * scale,
                                acc[r][2] * scale, acc[r][3] * scale);
        *(float4*)&Cb[(long)(i0 + ty * 4 + r) * ldc + j0 + tx * 4] = o0;
    }
    if (mode == 1) {
#pragma unroll
        for (int r = 0; r < 4; ++r) {
            float pr = acc[r][0] * bth[j0 + tx * 4 + 0]
                     + acc[r][1] * bth[j0 + tx * 4 + 1]
                     + acc[r][2] * bth[j0 + tx * 4 + 2]
                     + acc[r][3] * bth[j0 + tx * 4 + 3];
            pr += __shfl_xor(pr, 1); pr += __shfl_xor(pr, 2);
            pr += __shfl_xor(pr, 4); pr += __shfl_xor(pr, 8);
            if (tx == 0) atomicAdd(&be[b * C_ + i0 + ty * 4 + r], pr);
        }
    }
}

// ---- SP (NT) = P1 Wph^T + rank-1 epilogue -----------------------------------
__global__ __launch_bounds__(256) void gemm_nt_sp(
    const float* __restrict__ P1, const float* __restrict__ Wph,
    float* __restrict__ SP, const float* __restrict__ u1,
    const float* __restrict__ u2, const float* __restrict__ bg,
    const float* __restrict__ bph)
{
    int b = blockIdx.z;
    const float* Ab = P1 + (long)b * (CI_ * C_);
    int i0 = blockIdx.y * 64, j0 = blockIdx.x * 64;

    __shared__ __align__(16) float As[16][64];
    __shared__ __align__(16) float Bs[16][64];

    int t = threadIdx.x, tx = t & 15, ty = t >> 4;
    int lr = t >> 2, lk = (t & 3) << 2;

    float acc[4][4];
#pragma unroll
    for (int r = 0; r < 4; ++r)
#pragma unroll
        for (int c = 0; c < 4; ++c) acc[r][c] = 0.f;

    for (int kt = 0; kt < C_; kt += 16) {
        float4 va = *(const float4*)&Ab[(long)(i0 + lr) * C_ + kt + lk];
        float4 vb = *(const float4*)&Wph[(long)(j0 + lr) * C_ + kt + lk];
        As[lk + 0][lr] = va.x; As[lk + 1][lr] = va.y; As[lk + 2][lr] = va.z; As[lk + 3][lr] = va.w;
        Bs[lk + 0][lr] = vb.x; Bs[lk + 1][lr] = vb.y; Bs[lk + 2][lr] = vb.z; Bs[lk + 3][lr] = vb.w;
        __syncthreads();
#pragma unroll
        for (int k = 0; k < 16; ++k) {
            float4 a4 = *(float4*)&As[k][ty * 4];
            float4 b4 = *(float4*)&Bs[k][tx * 4];
            float a[4]  = {a4.x, a4.y, a4.z, a4.w};
            float bb[4] = {b4.x, b4.y, b4.z, b4.w};
#pragma unroll
            for (int r = 0; r < 4; ++r)
#pragma unroll
                for (int c = 0; c < 4; ++c)
                    acc[r][c] += a[r] * bb[c];
        }
        __syncthreads();
    }
    float* Cb = SP + (long)b * (CI_ * CI_);
#pragma unroll
    for (int r = 0; r < 4; ++r) {
        int cr = i0 + ty * 4 + r;
        float u1v = u1[b * CI_ + cr], bgv = bg[cr];
        float4 o0;
        float* po = (float*)&o0;
#pragma unroll
        for (int c = 0; c < 4; ++c) {
            int ic = j0 + tx * 4 + c;
            po[c] = acc[r][c] + u1v * bph[ic] + bgv * (u2[b * CI_ + ic] + (float)N_ * bph[ic]);
        }
        *(float4*)&Cb[(long)cr * CI_ + j0 + tx * 4] = o0;
    }
}

// ---- rank1_prep: u1 = Wg r, u2 = Wph r --------------------------------------
__global__ __launch_bounds__(256) void rank1_prep(
    const float* __restrict__ Wg, const float* __restrict__ Wph,
    const float* __restrict__ r, float* __restrict__ u1, float* __restrict__ u2)
{
    int blk = blockIdx.x;
    int b = blk >> 2, q = blk & 3;
    int t = threadIdx.x;
    int c = q * 64 + (t >> 2);
    int kq = t & 3;
    const float* rb = r + b * C_;
    float s1 = 0.f, s2 = 0.f;
    for (int k = kq * 128; k < kq * 128 + 128; k += 4) {
        float4 wg = *(const float4*)&Wg[(long)c * C_ + k];
        float4 wp = *(const float4*)&Wph[(long)c * C_ + k];
        float4 rv = *(const float4*)&rb[k];
        s1 += wg.x * rv.x + wg.y * rv.y + wg.z * rv.z + wg.w * rv.w;
        s2 += wp.x * rv.x + wp.y * rv.y + wp.z * rv.z + wp.w * rv.w;
    }
    s1 += __shfl_xor(s1, 1); s2 += __shfl_xor(s2, 1);
    s1 += __shfl_xor(s1, 2); s2 += __shfl_xor(s2, 2);
    if (kq == 0) {
        u1[b * CI_ + c] = s1;
        u2[b * CI_ + c] = s2;
    }
}

// ---- launch -----------------------------------------------------------------
extern "C" void kernel_launch(void* const* d_in, const int* in_sizes, int n_in,
                              void* d_out, int out_size, void* d_ws, size_t ws_size,
                              hipStream_t stream)
{
    const float* v     = (const float*)d_in[0];
    const float* Wg    = (const float*)d_in[1];
    const float* bg    = (const float*)d_in[2];
    const float* Wth   = (const float*)d_in[3];
    const float* bth   = (const float*)d_in[4];
    const float* Wph   = (const float*)d_in[5];
    const float* bph   = (const float*)d_in[6];
    const float* Ww    = (const float*)d_in[7];
    const float* bw    = (const float*)d_in[8];
    const float* gamma = (const float*)d_in[9];
    const float* beta  = (const float*)d_in[10];
    float* out = (float*)d_out;
    float* ws  = (float*)d_ws;

    float* G    = ws + G_OFF;
    float* H    = ws + H_OFF;
    float* P1   = ws + P1_OFF;
    float* SP   = ws + SP_OFF;
    float* P2   = ws + P2_OFF;
    float* r    = ws + R_OFF;
    float* be   = ws + BE_OFF;
    float* u1   = ws + U1_OFF;
    float* u2   = ws + U2_OFF;
    float* QF   = ws + QF_OFF;
    float* MV   = ws + MV_OFF;
    float* sc   = ws + SC_OFF;
    float* sh   = ws + SH_OFF;
    float* Gp   = ws + GP_OFF;
    unsigned short* Gh  = (unsigned short*)(ws + GH_OFF);
    unsigned short* vh  = (unsigned short*)(ws + VH_OFF);
    unsigned short* vl  = (unsigned short*)(ws + VL_OFF);
    unsigned short* vth = (unsigned short*)(ws + VTH_OFF);
    unsigned short* weh = (unsigned short*)(ws + WEH_OFF);
    unsigned short* wel = (unsigned short*)(ws + WEL_OFF);

    // zero atomic targets: r + be (contiguous 4096 floats). G no longer memset.
    hipMemsetAsync(r, 0, 4096 * sizeof(float), stream);

    // v -> vh, vl, vth, rowsums
    cast_fused<<<dim3(64, 8, 4), 256, 0, stream>>>(v, vh, vl, vth, r);

    // G lower-triangle partials (split-K=8, streaming), then reduce+mirror+cast
    gram_mfma<<<dim3(10, 1, 32), 256, 0, stream>>>(vh, vl, Gp);
    reduce_mirror<<<dim3(4, 10, 4), 256, 0, stream>>>(Gp, G, Gh);

    // u1 = Wg r, u2 = Wph r
    rank1_prep<<<16, 256, 0, stream>>>(Wg, Wph, r, u1, u2);

    // P1 = Wg G
    gemm_nn<<<dim3(8, 4, 4), 256, 0, stream>>>(
        Wg, 0, C_, G, (long)C_ * C_, C_, P1, (long)CI_ * C_, C_,
        C_, 1.0f, 0, nullptr, nullptr, nullptr, nullptr);

    // S' = P1 Wph^T + rank-1
    gemm_nt_sp<<<dim3(4, 4, 4), 256, 0, stream>>>(P1, Wph, SP, u1, u2, bg, bph);

    // P2 = Ww S' + be atomics
    gemm_nn<<<dim3(4, 8, 4), 256, 0, stream>>>(
        Ww, 0, CI_, SP, (long)CI_ * CI_, CI_, P2, (long)C_ * CI_, CI_,
        CI_, 1.0f, 1, bth, be, nullptr, nullptr);

    // Weff = (1/N) P2 Wth -> bf16 hi/lo
    gemm_nn<<<dim3(8, 8, 4), 256, 0, stream>>>(
        P2, (long)C_ * CI_, CI_, Wth, 0, C_, nullptr, 0, 0,
        CI_, 1.0f / (float)N_, 2, nullptr, nullptr, weh, wel);

    // analytic BN stats: H = Weff G ; QF/MV ; sc,sh
    h_mfma<<<dim3(4, 4, 4), 256, 0, stream>>>(weh, wel, Gh, H);
    stats_k<<<2048, 256, 0, stream>>>(H, weh, wel, r, QF, MV);
    finalize_k<<<1, 512, 0, stream>>>(QF, MV, be, bw, gamma, beta, sc, sh);

    // Wy with fused BN apply + residual
    wy_mfma<<<dim3(32, 4, 4), 256, 0, stream>>>(weh, wel, vth, be, bw, sc, sh, v, out);
}